// Round 20
// baseline (230.078 us; speedup 1.0000x reference)
//
#include <hip/hip_runtime.h>
#include <math.h>

typedef unsigned short u16;
typedef unsigned int u32;
typedef __attribute__((ext_vector_type(8))) __bf16 bf16x8;
typedef __attribute__((ext_vector_type(4))) float f32x4;
typedef __attribute__((ext_vector_type(16))) float f32x16;

#define DEVI __device__ __forceinline__

DEVI u16 f2bf(float f){
  u32 b = __builtin_bit_cast(u32, f);
  return (u16)((b + 0x7FFFu + ((b >> 16) & 1u)) >> 16);
}

// packed bf16 convert: lo = bf16(a), hi = bf16(b)
DEVI u32 cvtpk(float a, float b){
  u32 r;
  asm("v_cvt_pk_bf16_f32 %0, %1, %2" : "=v"(r) : "v"(a), "v"(b));
  return r;
}

DEVI f32x4 mfma16(bf16x8 a, bf16x8 b, f32x4 c){
  return __builtin_amdgcn_mfma_f32_16x16x32_bf16(a, b, c, 0, 0, 0);
}
DEVI f32x16 mfma32(bf16x8 a, bf16x8 b, f32x16 c){
  return __builtin_amdgcn_mfma_f32_32x32x16_bf16(a, b, c, 0, 0, 0);
}

// async global->LDS, 16B per lane; LDS dest = wave-uniform base + lane*16.
DEVI void gload16(const u16* g, u16* l){
  __builtin_amdgcn_global_load_lds(
      (const __attribute__((address_space(1))) u32*)g,
      (__attribute__((address_space(3))) u32*)l,
      16, 0, 0);
}

DEVI void phase_bar(){
  __builtin_amdgcn_sched_barrier(0);
  __builtin_amdgcn_s_barrier();
  __builtin_amdgcn_sched_barrier(0);
}

DEVI bf16x8 scale_bf16x8(bf16x8 v, float s){
  u32 w[4]; __builtin_memcpy(w, &v, 16);
  u32 o[4];
  #pragma unroll
  for (int i = 0; i < 4; ++i){
    float f0 = __builtin_bit_cast(float, (w[i] & 0xFFFFu) << 16) * s;
    float f1 = __builtin_bit_cast(float, w[i] & 0xFFFF0000u) * s;
    o[i] = (u32)f2bf(f0) | ((u32)f2bf(f1) << 16);
  }
  bf16x8 r; __builtin_memcpy(&r, o, 16);
  return r;
}

// ---------------- cvt body: 4 f32 -> 4 bf16 per thread ----------------
DEVI void cvt_body(const float* __restrict__ in, u16* __restrict__ out, int i){
  float4 v = reinterpret_cast<const float4*>(in)[i];
  u32 lo = (u32)f2bf(v.x) | ((u32)f2bf(v.y) << 16);
  u32 hi = (u32)f2bf(v.z) | ((u32)f2bf(v.w) << 16);
  reinterpret_cast<uint2*>(out)[i] = make_uint2(lo, hi);
}

// ---------------- LN body: f32 in, bf16 out, row length 1024 ----------------
DEVI void ln_body(const float* __restrict__ x, const float* __restrict__ w,
                  const float* __restrict__ b, u16* __restrict__ out,
                  int row, int tid, float* red){
  const float4 v = reinterpret_cast<const float4*>(x + (size_t)row * 1024)[tid];
  float s  = v.x + v.y + v.z + v.w;
  float ss = v.x*v.x + v.y*v.y + v.z*v.z + v.w*v.w;
  #pragma unroll
  for (int m = 1; m < 64; m <<= 1){
    s  += __shfl_xor(s,  m, 64);
    ss += __shfl_xor(ss, m, 64);
  }
  int wid = tid >> 6, lane = tid & 63;
  if (lane == 0){ red[wid] = s; red[4 + wid] = ss; }
  __syncthreads();
  s  = red[0] + red[1] + red[2] + red[3];
  ss = red[4] + red[5] + red[6] + red[7];
  float mu   = s * (1.0f/1024.0f);
  float var  = ss * (1.0f/1024.0f) - mu*mu;
  float rstd = rsqrtf(var + 1e-5f);
  const float4 wv = reinterpret_cast<const float4*>(w)[tid];
  const float4 bv = reinterpret_cast<const float4*>(b)[tid];
  u32 lo = (u32)f2bf((v.x-mu)*rstd*wv.x + bv.x) | ((u32)f2bf((v.y-mu)*rstd*wv.y + bv.y) << 16);
  u32 hi = (u32)f2bf((v.z-mu)*rstd*wv.z + bv.z) | ((u32)f2bf((v.w-mu)*rstd*wv.w + bv.w) << 16);
  reinterpret_cast<uint2*>(out + (size_t)row*1024)[tid] = make_uint2(lo, hi);
}

// ---------------- fused prep: 4 weight cvts + ln1, one launch ----------------
__global__ __launch_bounds__(256) void prep_kernel(const float* __restrict__ c_proj_w,
                                                   const float* __restrict__ proj_w,
                                                   const float* __restrict__ ffn1_w,
                                                   const float* __restrict__ ffn2_w,
                                                   const float* __restrict__ x,
                                                   const float* __restrict__ ln1_w,
                                                   const float* __restrict__ ln1_b,
                                                   u16* __restrict__ Wqkv,
                                                   u16* __restrict__ Wproj,
                                                   u16* __restrict__ Wff1,
                                                   u16* __restrict__ Wff2,
                                                   u16* __restrict__ LNb){
  __shared__ float red[8];
  const int bid = blockIdx.x;
  const int tid = threadIdx.x;
  if (bid < 3072){
    cvt_body(c_proj_w, Wqkv, bid*256 + tid);
  } else if (bid < 4096){
    cvt_body(proj_w, Wproj, (bid - 3072)*256 + tid);
  } else if (bid < 8192){
    cvt_body(ffn1_w, Wff1, (bid - 4096)*256 + tid);
  } else if (bid < 12288){
    cvt_body(ffn2_w, Wff2, (bid - 8192)*256 + tid);
  } else {
    ln_body(x, ln1_w, ln1_b, LNb, bid - 12288, tid, red);
  }
}

// ---------------- standalone LN (for ln2) ----------------
__global__ __launch_bounds__(256) void ln_kernel(const float* __restrict__ x,
                                                 const float* __restrict__ w,
                                                 const float* __restrict__ b,
                                                 u16* __restrict__ out){
  __shared__ float red[8];
  ln_body(x, w, b, out, blockIdx.x, threadIdx.x, red);
}

// ---------------- reduce: out = x + bias + sum of 4 bf16 partials (f32 out) --------
__global__ __launch_bounds__(256) void reduce4_kernel(const u16* __restrict__ P,
                                                      const float* __restrict__ x,
                                                      const float* __restrict__ bias,
                                                      float* __restrict__ out){
  const size_t i8 = ((size_t)blockIdx.x * 256 + threadIdx.x) * 8;
  const size_t PS = (size_t)4096 * 1024;
  const int col0 = (int)(i8 & 1023);
  float acc[8];
  #pragma unroll
  for (int j = 0; j < 8; ++j) acc[j] = bias[col0 + j];
  #pragma unroll
  for (int s = 0; s < 4; ++s){
    uint4 d = *reinterpret_cast<const uint4*>(P + s*PS + i8);
    u32 w[4] = {d.x, d.y, d.z, d.w};
    #pragma unroll
    for (int j = 0; j < 8; ++j){
      u32 bits = ((w[j>>1] >> (16*(j&1))) & 0xFFFFu) << 16;
      acc[j] += __builtin_bit_cast(float, bits);
    }
  }
  float4 xv0 = reinterpret_cast<const float4*>(x + i8)[0];
  float4 xv1 = reinterpret_cast<const float4*>(x + i8)[1];
  acc[0]+=xv0.x; acc[1]+=xv0.y; acc[2]+=xv0.z; acc[3]+=xv0.w;
  acc[4]+=xv1.x; acc[5]+=xv1.y; acc[6]+=xv1.z; acc[7]+=xv1.w;
  reinterpret_cast<float4*>(out + i8)[0] = make_float4(acc[0],acc[1],acc[2],acc[3]);
  reinterpret_cast<float4*>(out + i8)[1] = make_float4(acc[4],acc[5],acc[6],acc[7]);
}

// ============ 256x256 8-phase GEMM: C = A(M x lda) * W(N x lda)^T, bf16 out ========
template<bool HAS_BIAS, bool RELU, bool SPLIT>
__global__ __launch_bounds__(512, 2) void gemm256(const u16* __restrict__ A,
                                                  const u16* __restrict__ W,
                                                  const float* __restrict__ bias,
                                                  u16* __restrict__ outp,
                                                  int M, int N, int lda, int kLen){
  const int tid = threadIdx.x;
  const int wid = tid >> 6, lane = tid & 63;
  const int l16 = lane & 15, lhi = lane >> 4;
  const int wr = wid >> 2, wc = wid & 3;

  const int gx = gridDim.x, gy = gridDim.y;
  const int nwg = gx * gy * gridDim.z;
  const int bid = (blockIdx.z * gy + blockIdx.y) * gx + blockIdx.x;
  const int swz = (bid & 7) * (nwg >> 3) + (bid >> 3);
  const int col = swz % gx;
  const int rs  = swz / gx;
  const int row = rs % gy;
  const int ksp = rs / gy;
  const int brow = row * 256;
  const int bcol = col * 256;
  const size_t koff = (size_t)ksp * kLen;
  if (SPLIT) outp += (size_t)ksp * M * N;

  __shared__ u16 LDS[2][2][2][256*32];   // 128 KiB

  const int srow = tid >> 2;
  const int cg   = (tid & 3) ^ ((tid >> 3) & 3);
  const u16* gA = A + (size_t)(brow + srow) * lda + koff + cg*8;
  const u16* gW = W + (size_t)(bcol + srow) * lda + koff + cg*8;
  const size_t rK = (size_t)128 * lda;

#define STAGE(buf, mat, ks, t) do {                                   \
    const u16* _s = ((mat) ? gW : gA) + (t)*64 + (ks)*32;             \
    u16* _d = &LDS[buf][mat][ks][(wid*16)*32];                        \
    gload16(_s,      _d);                                             \
    gload16(_s + rK, _d + 128*32);                                    \
  } while(0)

  const int cswz = (lhi ^ ((l16 >> 1) & 3)) * 8;
  const int aoff = (wr*128 + l16)*32 + cswz;
  const int boff = (wc*64  + l16)*32 + cswz;
#define RDA(buf, ks, m) (*reinterpret_cast<const bf16x8*>(&LDS[buf][0][ks][aoff + (m)*512]))
#define RDB(buf, ks, n) (*reinterpret_cast<const bf16x8*>(&LDS[buf][1][ks][boff + (n)*512]))

  f32x4 acc[8][4] = {};
  bf16x8 a[8], b0, b1;

#define MFMA_PH(n0, n1) do {                                          \
    __builtin_amdgcn_s_setprio(1);                                    \
    _Pragma("unroll")                                                 \
    for (int m = 0; m < 8; ++m){                                      \
      acc[m][n0] = mfma16(a[m], b0, acc[m][n0]);                      \
      acc[m][n1] = mfma16(a[m], b1, acc[m][n1]);                      \
    }                                                                 \
    __builtin_amdgcn_s_setprio(0);                                    \
  } while(0)

  const int NITER = kLen >> 7;

  STAGE(0,0,0,0); STAGE(0,1,0,0); STAGE(0,0,1,0); STAGE(0,1,1,0);
  STAGE(1,0,0,1); STAGE(1,1,0,1);
  asm volatile("s_waitcnt vmcnt(4)" ::: "memory");
  phase_bar();

  for (int j = 0; j < NITER; ++j){
    const int t0 = 2*j, t1 = 2*j + 1;
    const bool more = (j + 1 < NITER);

    #pragma unroll
    for (int m = 0; m < 8; ++m) a[m] = RDA(0,0,m);
    b0 = RDB(0,0,0); b1 = RDB(0,0,1);
    STAGE(1,0,1,t1);
    phase_bar();
    MFMA_PH(0,1);
    phase_bar();
    b0 = RDB(0,0,2); b1 = RDB(0,0,3);
    STAGE(1,1,1,t1);
    phase_bar();
    MFMA_PH(2,3);
    phase_bar();
    #pragma unroll
    for (int m = 0; m < 8; ++m) a[m] = RDA(0,1,m);
    b0 = RDB(0,1,0); b1 = RDB(0,1,1);
    if (more) STAGE(0,0,0,t0+2);
    phase_bar();
    MFMA_PH(0,1);
    phase_bar();
    b0 = RDB(0,1,2); b1 = RDB(0,1,3);
    if (more){ STAGE(0,1,0,t0+2); asm volatile("s_waitcnt vmcnt(4)" ::: "memory"); }
    else     {                    asm volatile("s_waitcnt vmcnt(0)" ::: "memory"); }
    phase_bar();
    MFMA_PH(2,3);
    phase_bar();
    #pragma unroll
    for (int m = 0; m < 8; ++m) a[m] = RDA(1,0,m);
    b0 = RDB(1,0,0); b1 = RDB(1,0,1);
    if (more) STAGE(0,0,1,t0+2);
    phase_bar();
    MFMA_PH(0,1);
    phase_bar();
    b0 = RDB(1,0,2); b1 = RDB(1,0,3);
    if (more) STAGE(0,1,1,t0+2);
    phase_bar();
    MFMA_PH(2,3);
    phase_bar();
    #pragma unroll
    for (int m = 0; m < 8; ++m) a[m] = RDA(1,1,m);
    b0 = RDB(1,1,0); b1 = RDB(1,1,1);
    if (more) STAGE(1,0,0,t1+2);
    phase_bar();
    MFMA_PH(0,1);
    phase_bar();
    b0 = RDB(1,1,2); b1 = RDB(1,1,3);
    if (more){ STAGE(1,1,0,t1+2); asm volatile("s_waitcnt vmcnt(4)" ::: "memory"); }
    phase_bar();
    MFMA_PH(2,3);
    phase_bar();
  }
  __builtin_amdgcn_sched_barrier(0);

  const int row0 = brow + wr*128;
  const int col0 = bcol + wc*64;
  #pragma unroll
  for (int m = 0; m < 8; ++m){
    #pragma unroll
    for (int n = 0; n < 4; ++n){
      #pragma unroll
      for (int r = 0; r < 4; ++r){
        int row_ = row0 + m*16 + 4*lhi + r;
        int col_ = col0 + n*16 + l16;
        float v = acc[m][n][r];
        if constexpr (HAS_BIAS) v += bias[col_];
        if constexpr (RELU)     v = fmaxf(v, 0.0f);
        outp[(size_t)row_ * N + col_] = f2bf(v);
      }
    }
  }
#undef STAGE
#undef RDA
#undef RDB
#undef MFMA_PH
}

// ---------------- GEMM 128x128 (R7 structure) for proj ----------------
template<bool HAS_BIAS, bool HAS_RES, bool RELU, bool OUT_BF16>
__global__ __launch_bounds__(256) void gemm_bt(const u16* __restrict__ A,
                                               const u16* __restrict__ W,
                                               const float* __restrict__ bias,
                                               const float* __restrict__ res,
                                               void* __restrict__ outp,
                                               int M, int N, int K){
  const int tid = threadIdx.x;
  const int wid = tid >> 6, lane = tid & 63;
  const int l16 = lane & 15, lhi = lane >> 4;
  const int wr = wid >> 1, wc = wid & 1;

  const int gx = gridDim.x;
  const int nwg = gx * gridDim.y;
  const int bid = blockIdx.y * gx + blockIdx.x;
  const int swz = (bid & 7) * (nwg >> 3) + (bid >> 3);
  const int brow = (swz / gx) * 128;
  const int bcol = (swz % gx) * 128;

  __shared__ u16 As[2][128*32];
  __shared__ u16 Bs[2][128*32];

  const int srow = wid*32 + (lane >> 2);
  const int schk = lane & 3;
  const u16* gA0 = A + (size_t)(brow + srow)      * K + schk*8;
  const u16* gA1 = A + (size_t)(brow + srow + 16) * K + schk*8;
  const u16* gW0 = W + (size_t)(bcol + srow)      * K + schk*8;
  const u16* gW1 = W + (size_t)(bcol + srow + 16) * K + schk*8;
  const int ldsA0 = (wid*32)*32, ldsA1 = (wid*32 + 16)*32;

  f32x4 acc[4][4] = {};

  gload16(gA0, &As[0][ldsA0]);
  gload16(gA1, &As[0][ldsA1]);
  gload16(gW0, &Bs[0][ldsA0]);
  gload16(gW1, &Bs[0][ldsA1]);

  int cur = 0;
  for (int k0 = 0; k0 < K; k0 += 32){
    __syncthreads();
    if (k0 + 32 < K){
      gload16(gA0 + k0 + 32, &As[cur^1][ldsA0]);
      gload16(gA1 + k0 + 32, &As[cur^1][ldsA1]);
      gload16(gW0 + k0 + 32, &Bs[cur^1][ldsA0]);
      gload16(gW1 + k0 + 32, &Bs[cur^1][ldsA1]);
    }
    bf16x8 af[4], bfr[4];
    #pragma unroll
    for (int m = 0; m < 4; ++m)
      af[m]  = *reinterpret_cast<const bf16x8*>(&As[cur][(wr*64 + m*16 + l16)*32 + 8*lhi]);
    #pragma unroll
    for (int n = 0; n < 4; ++n)
      bfr[n] = *reinterpret_cast<const bf16x8*>(&Bs[cur][(wc*64 + n*16 + l16)*32 + 8*lhi]);
    #pragma unroll
    for (int m = 0; m < 4; ++m){
      #pragma unroll
      for (int n = 0; n < 4; ++n){
        acc[m][n] = mfma16(af[m], bfr[n], acc[m][n]);
      }
    }
    cur ^= 1;
  }

  const int row0 = brow + wr*64;
  const int col0 = bcol + wc*64;
  #pragma unroll
  for (int m = 0; m < 4; ++m){
    #pragma unroll
    for (int n = 0; n < 4; ++n){
      #pragma unroll
      for (int r = 0; r < 4; ++r){
        int row = row0 + m*16 + 4*lhi + r;
        int col = col0 + n*16 + l16;
        float v = acc[m][n][r];
        if constexpr (HAS_BIAS) v += bias[col];
        if constexpr (RELU)     v = fmaxf(v, 0.0f);
        if constexpr (HAS_RES)  v += res[(size_t)row * N + col];
        if constexpr (OUT_BF16) ((u16*)outp)[(size_t)row * N + col] = f2bf(v);
        else                    ((float*)outp)[(size_t)row * N + col] = v;
      }
    }
  }
}

// ====== causal flash attention: 32x32 swapped-QK, intra-block split-KV ======
// R19 structure; K fragments now read DIRECT FROM GLOBAL (L2-hit, XCD-local) —
// removes K staging writes + K LDS reads from the per-CU DS pipe (~40% of its load).
// V stays LDS-transposed (v_perm pack). LDS: Vt only (21.5 KB).
__global__ __launch_bounds__(256) void attn_kernel(const u16* __restrict__ qkv,
                                                   u16* __restrict__ att){
  const int bh = blockIdx.x;          // XCD-local (id%8 == bh%8)
  const int g  = 31 - blockIdx.y;     // heavy blocks dispatch first
  const int bb = bh >> 4, hh = bh & 15;
  const int tid = threadIdx.x;
  const int wid = tid >> 6, lane = tid & 63;
  const int half = wid >> 1;          // KV-range half
  const int p    = wid & 1;           // q-subtile
  const int l31 = lane & 31, h = lane >> 5;
  const u16* base = qkv + (size_t)bb * 2048 * 3072 + (size_t)hh * 192;

  __shared__ __align__(16) u16 Vt[2][64*80];   // 20480 B (combine O-buf reuses)
  __shared__ __align__(16) float mlb[258];     // combine (m,l) buffer

  // V staging mapping within each half's 128 threads
  const int th = tid & 127;
  const int va = th >> 2, vd = (th & 3) * 16;
  const u16* vstage = base + (size_t)(2*va) * 3072 + 128 + vd;

  const int qrow0 = g*64 + p*32;
  const int q = qrow0 + l31;

  const float QSCALE = 0.125f * 1.44269504f;   // exp2 domain
  bf16x8 qb[4];
  {
    const u16* qp = base + (size_t)q * 3072 + 64 + 8*h;
    #pragma unroll
    for (int s = 0; s < 4; ++s)
      qb[s] = scale_bf16x8(*reinterpret_cast<const bf16x8*>(qp + 16*s), QSCALE);
  }

  f32x16 o0 = (f32x16)0.0f, o1 = (f32x16)0.0f;
  float m = -INFINITY, l = 0.0f;

  const int h0  = (g + 2) >> 1;            // ceil((g+1)/2) = half A length
  const int lo  = half ? h0 : 0;
  const int len = half ? (g + 1 - h0) : h0;

  uint4 v00, v01, v10, v11;
#define LOADV(t) do {                                                  \
    const u16* vp = vstage + (size_t)(t) * 64 * 3072;                  \
    v00 = *reinterpret_cast<const uint4*>(vp);                         \
    v01 = *reinterpret_cast<const uint4*>(vp + 8);                     \
    v10 = *reinterpret_cast<const uint4*>(vp + 3072);                  \
    v11 = *reinterpret_cast<const uint4*>(vp + 3072 + 8);              \
  } while(0)

  if (len > 0) LOADV(lo);

  for (int it = 0; it < h0; ++it){
    const int kt = lo + it;
    const bool act = it < len;

    __syncthreads();               // previous tile's LDS reads complete (block-wide)
    if (act){
      u32 w00[4] = {v00.x, v00.y, v00.z, v00.w};
      u32 w01[4] = {v01.x, v01.y, v01.z, v01.w};
      u32 w10[4] = {v10.x, v10.y, v10.z, v10.w};
      u32 w11[4] = {v11.x, v11.y, v11.z, v11.w};
      // pack V[2va][d] | V[2va+1][d]<<16 with one v_perm_b32 per output word
      #pragma unroll
      for (int j = 0; j < 16; ++j){
        u32 a = (j < 8) ? w10[j>>1] : w11[(j-8)>>1];   // k row 2va+1 source
        u32 b = (j < 8) ? w00[j>>1] : w01[(j-8)>>1];   // k row 2va   source
        u32 packed = __builtin_amdgcn_perm(a, b, (j & 1) ? 0x07060302u : 0x05040100u);
        int d = vd + j;
        *reinterpret_cast<u32*>(&Vt[half][d*80 + (((va>>2) ^ (d>>3)) << 3) + 2*(va&3)]) =
            packed;
      }
    }
    __syncthreads();               // V staged

    if (!act) continue;            // short half idles (after barriers)

    // ---- K fragments direct from global (L2-resident, XCD-local) ----
    bf16x8 kf0[4], kf1[4];
    {
      const u16* kr0 = base + (size_t)(kt*64 + l31) * 3072 + 8*h;
      #pragma unroll
      for (int s = 0; s < 4; ++s){
        kf0[s] = *reinterpret_cast<const bf16x8*>(kr0 + 16*s);
        kf1[s] = *reinterpret_cast<const bf16x8*>(kr0 + 32*3072 + 16*s);
      }
    }

    if (it + 1 < len) LOADV(kt + 1);   // prefetch next V tile during compute

    const u16* VtC = &Vt[half][0];

    // ---- S^T = K . Q'^T ----
    f32x16 s0 = (f32x16)0.0f, s1 = (f32x16)0.0f;
    __builtin_amdgcn_s_setprio(1);
    #pragma unroll
    for (int s = 0; s < 4; ++s){
      s0 = mfma32(kf0[s], qb[s], s0);
      s1 = mfma32(kf1[s], qb[s], s1);
    }
    __builtin_amdgcn_s_setprio(0);

    if (kt == g){                  // diagonal tile: causal mask
      #pragma unroll
      for (int r = 0; r < 16; ++r){
        int krow = kt*64 + (r&3) + 8*(r>>2) + 4*h;
        if (krow > q)      s0[r] = -INFINITY;
        if (krow + 32 > q) s1[r] = -INFINITY;
      }
    }

    // ---- per-lane softmax; max via max3-shaped tree ----
    float t0_ = fmaxf(fmaxf(s0[0],  s0[1]),  s0[2]);
    float t1_ = fmaxf(fmaxf(s0[3],  s0[4]),  s0[5]);
    float t2_ = fmaxf(fmaxf(s0[6],  s0[7]),  s0[8]);
    float t3_ = fmaxf(fmaxf(s0[9],  s0[10]), s0[11]);
    float t4_ = fmaxf(fmaxf(s0[12], s0[13]), s0[14]);
    float t5_ = fmaxf(fmaxf(s0[15], s1[0]),  s1[1]);
    float t6_ = fmaxf(fmaxf(s1[2],  s1[3]),  s1[4]);
    float t7_ = fmaxf(fmaxf(s1[5],  s1[6]),  s1[7]);
    float t8_ = fmaxf(fmaxf(s1[8],  s1[9]),  s1[10]);
    float t9_ = fmaxf(fmaxf(s1[11], s1[12]), s1[13]);
    float ta_ = fmaxf(s1[14], s1[15]);
    float mxa = fmaxf(fmaxf(t0_, t1_), t2_);
    float mxb = fmaxf(fmaxf(t3_, t4_), t5_);
    float mxc = fmaxf(fmaxf(t6_, t7_), t8_);
    float mxd = fmaxf(t9_, ta_);
    float mx  = fmaxf(fmaxf(mxa, mxb), fmaxf(mxc, mxd));
    mx = fmaxf(mx, __shfl_xor(mx, 32, 64));
    if (__any(mx > m)){
      float mnew = fmaxf(m, mx);
      float al = exp2f(m - mnew);
      m = mnew;
      l *= al;
      o0 *= al;
      o1 *= al;
    }
    float p0[16], p1[16];
    float sa = 0.0f, sb = 0.0f, sc = 0.0f, sd = 0.0f;
    #pragma unroll
    for (int r = 0; r < 8; ++r){ p0[r] = exp2f(s0[r] - m); sa += p0[r]; }
    #pragma unroll
    for (int r = 8; r < 16; ++r){ p0[r] = exp2f(s0[r] - m); sb += p0[r]; }
    #pragma unroll
    for (int r = 0; r < 8; ++r){ p1[r] = exp2f(s1[r] - m); sc += p1[r]; }
    #pragma unroll
    for (int r = 8; r < 16; ++r){ p1[r] = exp2f(s1[r] - m); sd += p1[r]; }
    l += (sa + sb) + (sc + sd);

    u32 pk0[8], pk1[8];
    #pragma unroll
    for (int g4 = 0; g4 < 4; ++g4){
      pk0[2*g4]   = cvtpk(p0[4*g4],   p0[4*g4+1]);
      pk0[2*g4+1] = cvtpk(p0[4*g4+2], p0[4*g4+3]);
      pk1[2*g4]   = cvtpk(p1[4*g4],   p1[4*g4+1]);
      pk1[2*g4+1] = cvtpk(p1[4*g4+2], p1[4*g4+3]);
    }

    __builtin_amdgcn_s_setprio(1);
    #pragma unroll
    for (int s = 0; s < 4; ++s){
      const int gA = (s & 1) * 2;
      u32 oa0 = (s >> 1) ? pk1[2*gA]       : pk0[2*gA];
      u32 oa1 = (s >> 1) ? pk1[2*gA+1]     : pk0[2*gA+1];
      u32 ob0 = (s >> 1) ? pk1[2*(gA+1)]   : pk0[2*(gA+1)];
      u32 ob1 = (s >> 1) ? pk1[2*(gA+1)+1] : pk0[2*(gA+1)+1];
      u32 t0 = h ? oa0 : ob0;
      u32 t1 = h ? oa1 : ob1;
      u32 r0 = (u32)__shfl_xor((int)t0, 32, 64);
      u32 r1 = (u32)__shfl_xor((int)t1, 32, 64);
      u32 b0_ = h ? r0 : oa0;
      u32 b1_ = h ? r1 : oa1;
      u32 b2_ = h ? ob0 : r0;
      u32 b3_ = h ? ob1 : r1;
      bf16x8 pfrag = __builtin_bit_cast(bf16x8, make_uint4(b0_, b1_, b2_, b3_));
      bf16x8 vf0 = *reinterpret_cast<const bf16x8*>(
          &VtC[l31*80      + (((2*s + h) ^ (l31 >> 3)) << 3)]);
      bf16x8 vf1 = *reinterpret_cast<const bf16x8*>(
          &VtC[(32+l31)*80 + (((2*s + h) ^ ((32+l31) >> 3)) << 3)]);
      o0 = mfma32(vf0, pfrag, o0);
      o1 = mfma32(vf1, pfrag, o1);
    }
    __builtin_amdgcn_s_setprio(0);
  }

  // ---- in-block flash combine (A = half 0 waves, B = half 1 waves) ----
  __syncthreads();                       // all tile reads done; LDS reusable
  float* ob = (float*)&Vt[0][0];         // [32 r][128 pl] = 16 KB, conflict-free
  const int pl = p*64 + lane;

  l += __shfl_xor(l, 32, 64);            // full l per q for this half

  if (half == 1){
    #pragma unroll
    for (int r = 0; r < 16; ++r){
      ob[r*128 + pl]        = o0[r];
      ob[(16 + r)*128 + pl] = o1[r];
    }
    mlb[pl]       = m;
    mlb[pl + 128] = l;
  }
  __syncthreads();
  if (half == 0){
    float mB = mlb[pl], lB = mlb[pl + 128];
    float mS = fmaxf(m, mB);
    float sA = exp2f(m - mS), sB = exp2f(mB - mS);
    float inv = 1.0f / (l*sA + lB*sB);
    sA *= inv; sB *= inv;
    u16* orow = att + (size_t)(bb*2048 + q) * 1024 + hh*64;
    #pragma unroll
    for (int r = 0; r < 16; r += 2){
      int d0 = (r&3) + 8*(r>>2) + 4*h;
      float a0 = o0[r]*sA     + ob[r*128 + pl]*sB;
      float a1 = o0[r+1]*sA   + ob[(r+1)*128 + pl]*sB;
      float c0 = o1[r]*sA     + ob[(16+r)*128 + pl]*sB;
      float c1 = o1[r+1]*sA   + ob[(16+r+1)*128 + pl]*sB;
      *reinterpret_cast<u32*>(&orow[d0])      = cvtpk(a0, a1);
      *reinterpret_cast<u32*>(&orow[32 + d0]) = cvtpk(c0, c1);
    }
  }
#undef LOADV
}

extern "C" void kernel_launch(void* const* d_in, const int* in_sizes, int n_in,
                              void* d_out, int out_size, void* d_ws, size_t ws_size,
                              hipStream_t stream){
  const float* x        = (const float*)d_in[0];
  const float* ln1_w    = (const float*)d_in[1];
  const float* ln1_b    = (const float*)d_in[2];
  const float* c_proj_w = (const float*)d_in[3];
  const float* proj_w   = (const float*)d_in[4];
  const float* proj_b   = (const float*)d_in[5];
  const float* ln2_w    = (const float*)d_in[6];
  const float* ln2_b    = (const float*)d_in[7];
  const float* ffn1_w   = (const float*)d_in[8];
  const float* ffn1_b   = (const float*)d_in[9];
  const float* ffn2_w   = (const float*)d_in[10];
  const float* ffn2_b   = (const float*)d_in[11];

  // Workspace layout (80 MiB); tail region reused for ffn2 split-K partials.
  char* p = (char*)d_ws;
  u16* Wff1  = (u16*)p;  p += (size_t)4096*1024*2;   //  8 MiB
  u16* Wff2  = (u16*)p;  p += (size_t)1024*4096*2;   //  8 MiB
  u16* QKV   = (u16*)p;  p += (size_t)4096*3072*2;   // 24 MiB
  u16* ATT   = (u16*)p;  p += (size_t)4096*1024*2;   //  8 MiB
  u16* Wqkv  = (u16*)p;  p += (size_t)3072*1024*2;   //  6 MiB
  u16* Wproj = (u16*)p;  p += (size_t)1024*1024*2;   //  2 MiB
  u16* LNb   = (u16*)p;  p += (size_t)4096*1024*2;   //  8 MiB
  float* ACT2= (float*)p;                            // 16 MiB
  u16* FFN1  = QKV;
  u16* PART  = Wqkv;     // 32 MiB: Wqkv+Wproj+LNb+ACT2 all dead by ffn2 time

  prep_kernel<<<16384, 256, 0, stream>>>(c_proj_w, proj_w, ffn1_w, ffn2_w,
                                         x, ln1_w, ln1_b,
                                         Wqkv, Wproj, Wff1, Wff2, LNb);
  gemm256<false,false,false><<<dim3(12,16,1), 512, 0, stream>>>(LNb, Wqkv, nullptr, QKV, 4096, 3072, 1024, 1024);
  attn_kernel<<<dim3(32,32), 256, 0, stream>>>(QKV, ATT);
  gemm_bt<true ,true ,false,false><<<dim3(8,32), 256, 0, stream>>>(ATT, Wproj, proj_b, x, ACT2, 4096, 1024, 1024);
  ln_kernel<<<4096, 256, 0, stream>>>(ACT2, ln2_w, ln2_b, LNb);
  gemm256<true ,true ,false><<<dim3(16,16,1), 512, 0, stream>>>(LNb, Wff1, ffn1_b, FFN1, 4096, 4096, 1024, 1024);
  gemm256<false,false,true ><<<dim3(4,16,4), 512, 0, stream>>>(FFN1, Wff2, nullptr, PART, 4096, 1024, 4096, 1024);
  reduce4_kernel<<<2048, 256, 0, stream>>>(PART, x, ffn2_b, (float*)d_out);
}

// Round 21
// 223.881 us; speedup vs baseline: 1.0277x; 1.0277x over previous
//
#include <hip/hip_runtime.h>
#include <math.h>

typedef unsigned short u16;
typedef unsigned int u32;
typedef __attribute__((ext_vector_type(8))) __bf16 bf16x8;
typedef __attribute__((ext_vector_type(4))) float f32x4;
typedef __attribute__((ext_vector_type(16))) float f32x16;

#define DEVI __device__ __forceinline__

DEVI u16 f2bf(float f){
  u32 b = __builtin_bit_cast(u32, f);
  return (u16)((b + 0x7FFFu + ((b >> 16) & 1u)) >> 16);
}

// packed bf16 convert: lo = bf16(a), hi = bf16(b)
DEVI u32 cvtpk(float a, float b){
  u32 r;
  asm("v_cvt_pk_bf16_f32 %0, %1, %2" : "=v"(r) : "v"(a), "v"(b));
  return r;
}

DEVI f32x4 mfma16(bf16x8 a, bf16x8 b, f32x4 c){
  return __builtin_amdgcn_mfma_f32_16x16x32_bf16(a, b, c, 0, 0, 0);
}
DEVI f32x16 mfma32(bf16x8 a, bf16x8 b, f32x16 c){
  return __builtin_amdgcn_mfma_f32_32x32x16_bf16(a, b, c, 0, 0, 0);
}

// async global->LDS, 16B per lane; LDS dest = wave-uniform base + lane*16.
DEVI void gload16(const u16* g, u16* l){
  __builtin_amdgcn_global_load_lds(
      (const __attribute__((address_space(1))) u32*)g,
      (__attribute__((address_space(3))) u32*)l,
      16, 0, 0);
}

DEVI void phase_bar(){
  __builtin_amdgcn_sched_barrier(0);
  __builtin_amdgcn_s_barrier();
  __builtin_amdgcn_sched_barrier(0);
}

DEVI bf16x8 scale_bf16x8(bf16x8 v, float s){
  u32 w[4]; __builtin_memcpy(w, &v, 16);
  u32 o[4];
  #pragma unroll
  for (int i = 0; i < 4; ++i){
    float f0 = __builtin_bit_cast(float, (w[i] & 0xFFFFu) << 16) * s;
    float f1 = __builtin_bit_cast(float, w[i] & 0xFFFF0000u) * s;
    o[i] = (u32)f2bf(f0) | ((u32)f2bf(f1) << 16);
  }
  bf16x8 r; __builtin_memcpy(&r, o, 16);
  return r;
}

// ---------------- cvt body: 4 f32 -> 4 bf16 per thread ----------------
DEVI void cvt_body(const float* __restrict__ in, u16* __restrict__ out, int i){
  float4 v = reinterpret_cast<const float4*>(in)[i];
  u32 lo = (u32)f2bf(v.x) | ((u32)f2bf(v.y) << 16);
  u32 hi = (u32)f2bf(v.z) | ((u32)f2bf(v.w) << 16);
  reinterpret_cast<uint2*>(out)[i] = make_uint2(lo, hi);
}

// ---------------- LN body: f32 in, bf16 out, row length 1024 ----------------
DEVI void ln_body(const float* __restrict__ x, const float* __restrict__ w,
                  const float* __restrict__ b, u16* __restrict__ out,
                  int row, int tid, float* red){
  const float4 v = reinterpret_cast<const float4*>(x + (size_t)row * 1024)[tid];
  float s  = v.x + v.y + v.z + v.w;
  float ss = v.x*v.x + v.y*v.y + v.z*v.z + v.w*v.w;
  #pragma unroll
  for (int m = 1; m < 64; m <<= 1){
    s  += __shfl_xor(s,  m, 64);
    ss += __shfl_xor(ss, m, 64);
  }
  int wid = tid >> 6, lane = tid & 63;
  if (lane == 0){ red[wid] = s; red[4 + wid] = ss; }
  __syncthreads();
  s  = red[0] + red[1] + red[2] + red[3];
  ss = red[4] + red[5] + red[6] + red[7];
  float mu   = s * (1.0f/1024.0f);
  float var  = ss * (1.0f/1024.0f) - mu*mu;
  float rstd = rsqrtf(var + 1e-5f);
  const float4 wv = reinterpret_cast<const float4*>(w)[tid];
  const float4 bv = reinterpret_cast<const float4*>(b)[tid];
  u32 lo = (u32)f2bf((v.x-mu)*rstd*wv.x + bv.x) | ((u32)f2bf((v.y-mu)*rstd*wv.y + bv.y) << 16);
  u32 hi = (u32)f2bf((v.z-mu)*rstd*wv.z + bv.z) | ((u32)f2bf((v.w-mu)*rstd*wv.w + bv.w) << 16);
  reinterpret_cast<uint2*>(out + (size_t)row*1024)[tid] = make_uint2(lo, hi);
}

// ------- prep: c_proj & proj weight cvts + ln1 (ffn cvts moved into attn launch) ----
// blocks [0,3072): c_proj_w->Wqkv | [3072,4096): proj_w->Wproj | [4096,8192): ln1
__global__ __launch_bounds__(256) void prep_kernel(const float* __restrict__ c_proj_w,
                                                   const float* __restrict__ proj_w,
                                                   const float* __restrict__ x,
                                                   const float* __restrict__ ln1_w,
                                                   const float* __restrict__ ln1_b,
                                                   u16* __restrict__ Wqkv,
                                                   u16* __restrict__ Wproj,
                                                   u16* __restrict__ LNb){
  __shared__ float red[8];
  const int bid = blockIdx.x;
  const int tid = threadIdx.x;
  if (bid < 3072){
    cvt_body(c_proj_w, Wqkv, bid*256 + tid);
  } else if (bid < 4096){
    cvt_body(proj_w, Wproj, (bid - 3072)*256 + tid);
  } else {
    ln_body(x, ln1_w, ln1_b, LNb, bid - 4096, tid, red);
  }
}

// ---------------- standalone LN (for ln2) ----------------
__global__ __launch_bounds__(256) void ln_kernel(const float* __restrict__ x,
                                                 const float* __restrict__ w,
                                                 const float* __restrict__ b,
                                                 u16* __restrict__ out){
  __shared__ float red[8];
  ln_body(x, w, b, out, blockIdx.x, threadIdx.x, red);
}

// ---------------- reduce: out = x + bias + sum of 4 bf16 partials (f32 out) --------
__global__ __launch_bounds__(256) void reduce4_kernel(const u16* __restrict__ P,
                                                      const float* __restrict__ x,
                                                      const float* __restrict__ bias,
                                                      float* __restrict__ out){
  const size_t i8 = ((size_t)blockIdx.x * 256 + threadIdx.x) * 8;
  const size_t PS = (size_t)4096 * 1024;
  const int col0 = (int)(i8 & 1023);
  float acc[8];
  #pragma unroll
  for (int j = 0; j < 8; ++j) acc[j] = bias[col0 + j];
  #pragma unroll
  for (int s = 0; s < 4; ++s){
    uint4 d = *reinterpret_cast<const uint4*>(P + s*PS + i8);
    u32 w[4] = {d.x, d.y, d.z, d.w};
    #pragma unroll
    for (int j = 0; j < 8; ++j){
      u32 bits = ((w[j>>1] >> (16*(j&1))) & 0xFFFFu) << 16;
      acc[j] += __builtin_bit_cast(float, bits);
    }
  }
  float4 xv0 = reinterpret_cast<const float4*>(x + i8)[0];
  float4 xv1 = reinterpret_cast<const float4*>(x + i8)[1];
  acc[0]+=xv0.x; acc[1]+=xv0.y; acc[2]+=xv0.z; acc[3]+=xv0.w;
  acc[4]+=xv1.x; acc[5]+=xv1.y; acc[6]+=xv1.z; acc[7]+=xv1.w;
  reinterpret_cast<float4*>(out + i8)[0] = make_float4(acc[0],acc[1],acc[2],acc[3]);
  reinterpret_cast<float4*>(out + i8)[1] = make_float4(acc[4],acc[5],acc[6],acc[7]);
}

// ============ 256x256 8-phase GEMM: C = A(M x lda) * W(N x lda)^T, bf16 out ========
template<bool HAS_BIAS, bool RELU, bool SPLIT>
__global__ __launch_bounds__(512, 2) void gemm256(const u16* __restrict__ A,
                                                  const u16* __restrict__ W,
                                                  const float* __restrict__ bias,
                                                  u16* __restrict__ outp,
                                                  int M, int N, int lda, int kLen){
  const int tid = threadIdx.x;
  const int wid = tid >> 6, lane = tid & 63;
  const int l16 = lane & 15, lhi = lane >> 4;
  const int wr = wid >> 2, wc = wid & 3;

  const int gx = gridDim.x, gy = gridDim.y;
  const int nwg = gx * gy * gridDim.z;
  const int bid = (blockIdx.z * gy + blockIdx.y) * gx + blockIdx.x;
  const int swz = (bid & 7) * (nwg >> 3) + (bid >> 3);
  const int col = swz % gx;
  const int rs  = swz / gx;
  const int row = rs % gy;
  const int ksp = rs / gy;
  const int brow = row * 256;
  const int bcol = col * 256;
  const size_t koff = (size_t)ksp * kLen;
  if (SPLIT) outp += (size_t)ksp * M * N;

  __shared__ u16 LDS[2][2][2][256*32];   // 128 KiB

  const int srow = tid >> 2;
  const int cg   = (tid & 3) ^ ((tid >> 3) & 3);
  const u16* gA = A + (size_t)(brow + srow) * lda + koff + cg*8;
  const u16* gW = W + (size_t)(bcol + srow) * lda + koff + cg*8;
  const size_t rK = (size_t)128 * lda;

#define STAGE(buf, mat, ks, t) do {                                   \
    const u16* _s = ((mat) ? gW : gA) + (t)*64 + (ks)*32;             \
    u16* _d = &LDS[buf][mat][ks][(wid*16)*32];                        \
    gload16(_s,      _d);                                             \
    gload16(_s + rK, _d + 128*32);                                    \
  } while(0)

  const int cswz = (lhi ^ ((l16 >> 1) & 3)) * 8;
  const int aoff = (wr*128 + l16)*32 + cswz;
  const int boff = (wc*64  + l16)*32 + cswz;
#define RDA(buf, ks, m) (*reinterpret_cast<const bf16x8*>(&LDS[buf][0][ks][aoff + (m)*512]))
#define RDB(buf, ks, n) (*reinterpret_cast<const bf16x8*>(&LDS[buf][1][ks][boff + (n)*512]))

  f32x4 acc[8][4] = {};
  bf16x8 a[8], b0, b1;

#define MFMA_PH(n0, n1) do {                                          \
    __builtin_amdgcn_s_setprio(1);                                    \
    _Pragma("unroll")                                                 \
    for (int m = 0; m < 8; ++m){                                      \
      acc[m][n0] = mfma16(a[m], b0, acc[m][n0]);                      \
      acc[m][n1] = mfma16(a[m], b1, acc[m][n1]);                      \
    }                                                                 \
    __builtin_amdgcn_s_setprio(0);                                    \
  } while(0)

  const int NITER = kLen >> 7;

  STAGE(0,0,0,0); STAGE(0,1,0,0); STAGE(0,0,1,0); STAGE(0,1,1,0);
  STAGE(1,0,0,1); STAGE(1,1,0,1);
  asm volatile("s_waitcnt vmcnt(4)" ::: "memory");
  phase_bar();

  for (int j = 0; j < NITER; ++j){
    const int t0 = 2*j, t1 = 2*j + 1;
    const bool more = (j + 1 < NITER);

    #pragma unroll
    for (int m = 0; m < 8; ++m) a[m] = RDA(0,0,m);
    b0 = RDB(0,0,0); b1 = RDB(0,0,1);
    STAGE(1,0,1,t1);
    phase_bar();
    MFMA_PH(0,1);
    phase_bar();
    b0 = RDB(0,0,2); b1 = RDB(0,0,3);
    STAGE(1,1,1,t1);
    phase_bar();
    MFMA_PH(2,3);
    phase_bar();
    #pragma unroll
    for (int m = 0; m < 8; ++m) a[m] = RDA(0,1,m);
    b0 = RDB(0,1,0); b1 = RDB(0,1,1);
    if (more) STAGE(0,0,0,t0+2);
    phase_bar();
    MFMA_PH(0,1);
    phase_bar();
    b0 = RDB(0,1,2); b1 = RDB(0,1,3);
    if (more){ STAGE(0,1,0,t0+2); asm volatile("s_waitcnt vmcnt(4)" ::: "memory"); }
    else     {                    asm volatile("s_waitcnt vmcnt(0)" ::: "memory"); }
    phase_bar();
    MFMA_PH(2,3);
    phase_bar();
    #pragma unroll
    for (int m = 0; m < 8; ++m) a[m] = RDA(1,0,m);
    b0 = RDB(1,0,0); b1 = RDB(1,0,1);
    if (more) STAGE(0,0,1,t0+2);
    phase_bar();
    MFMA_PH(0,1);
    phase_bar();
    b0 = RDB(1,0,2); b1 = RDB(1,0,3);
    if (more) STAGE(0,1,1,t0+2);
    phase_bar();
    MFMA_PH(2,3);
    phase_bar();
    #pragma unroll
    for (int m = 0; m < 8; ++m) a[m] = RDA(1,1,m);
    b0 = RDB(1,1,0); b1 = RDB(1,1,1);
    if (more) STAGE(1,0,0,t1+2);
    phase_bar();
    MFMA_PH(0,1);
    phase_bar();
    b0 = RDB(1,1,2); b1 = RDB(1,1,3);
    if (more){ STAGE(1,1,0,t1+2); asm volatile("s_waitcnt vmcnt(4)" ::: "memory"); }
    phase_bar();
    MFMA_PH(2,3);
    phase_bar();
  }
  __builtin_amdgcn_sched_barrier(0);

  const int row0 = brow + wr*128;
  const int col0 = bcol + wc*64;
  #pragma unroll
  for (int m = 0; m < 8; ++m){
    #pragma unroll
    for (int n = 0; n < 4; ++n){
      #pragma unroll
      for (int r = 0; r < 4; ++r){
        int row_ = row0 + m*16 + 4*lhi + r;
        int col_ = col0 + n*16 + l16;
        float v = acc[m][n][r];
        if constexpr (HAS_BIAS) v += bias[col_];
        if constexpr (RELU)     v = fmaxf(v, 0.0f);
        outp[(size_t)row_ * N + col_] = f2bf(v);
      }
    }
  }
#undef STAGE
#undef RDA
#undef RDB
#undef MFMA_PH
}

// ---------------- GEMM 128x128 (R7 structure) for proj ----------------
template<bool HAS_BIAS, bool HAS_RES, bool RELU, bool OUT_BF16>
__global__ __launch_bounds__(256) void gemm_bt(const u16* __restrict__ A,
                                               const u16* __restrict__ W,
                                               const float* __restrict__ bias,
                                               const float* __restrict__ res,
                                               void* __restrict__ outp,
                                               int M, int N, int K){
  const int tid = threadIdx.x;
  const int wid = tid >> 6, lane = tid & 63;
  const int l16 = lane & 15, lhi = lane >> 4;
  const int wr = wid >> 1, wc = wid & 1;

  const int gx = gridDim.x;
  const int nwg = gx * gridDim.y;
  const int bid = blockIdx.y * gx + blockIdx.x;
  const int swz = (bid & 7) * (nwg >> 3) + (bid >> 3);
  const int brow = (swz / gx) * 128;
  const int bcol = (swz % gx) * 128;

  __shared__ u16 As[2][128*32];
  __shared__ u16 Bs[2][128*32];

  const int srow = wid*32 + (lane >> 2);
  const int schk = lane & 3;
  const u16* gA0 = A + (size_t)(brow + srow)      * K + schk*8;
  const u16* gA1 = A + (size_t)(brow + srow + 16) * K + schk*8;
  const u16* gW0 = W + (size_t)(bcol + srow)      * K + schk*8;
  const u16* gW1 = W + (size_t)(bcol + srow + 16) * K + schk*8;
  const int ldsA0 = (wid*32)*32, ldsA1 = (wid*32 + 16)*32;

  f32x4 acc[4][4] = {};

  gload16(gA0, &As[0][ldsA0]);
  gload16(gA1, &As[0][ldsA1]);
  gload16(gW0, &Bs[0][ldsA0]);
  gload16(gW1, &Bs[0][ldsA1]);

  int cur = 0;
  for (int k0 = 0; k0 < K; k0 += 32){
    __syncthreads();
    if (k0 + 32 < K){
      gload16(gA0 + k0 + 32, &As[cur^1][ldsA0]);
      gload16(gA1 + k0 + 32, &As[cur^1][ldsA1]);
      gload16(gW0 + k0 + 32, &Bs[cur^1][ldsA0]);
      gload16(gW1 + k0 + 32, &Bs[cur^1][ldsA1]);
    }
    bf16x8 af[4], bfr[4];
    #pragma unroll
    for (int m = 0; m < 4; ++m)
      af[m]  = *reinterpret_cast<const bf16x8*>(&As[cur][(wr*64 + m*16 + l16)*32 + 8*lhi]);
    #pragma unroll
    for (int n = 0; n < 4; ++n)
      bfr[n] = *reinterpret_cast<const bf16x8*>(&Bs[cur][(wc*64 + n*16 + l16)*32 + 8*lhi]);
    #pragma unroll
    for (int m = 0; m < 4; ++m){
      #pragma unroll
      for (int n = 0; n < 4; ++n){
        acc[m][n] = mfma16(af[m], bfr[n], acc[m][n]);
      }
    }
    cur ^= 1;
  }

  const int row0 = brow + wr*64;
  const int col0 = bcol + wc*64;
  #pragma unroll
  for (int m = 0; m < 4; ++m){
    #pragma unroll
    for (int n = 0; n < 4; ++n){
      #pragma unroll
      for (int r = 0; r < 4; ++r){
        int row = row0 + m*16 + 4*lhi + r;
        int col = col0 + n*16 + l16;
        float v = acc[m][n][r];
        if constexpr (HAS_BIAS) v += bias[col];
        if constexpr (RELU)     v = fmaxf(v, 0.0f);
        if constexpr (HAS_RES)  v += res[(size_t)row * N + col];
        if constexpr (OUT_BF16) ((u16*)outp)[(size_t)row * N + col] = f2bf(v);
        else                    ((float*)outp)[(size_t)row * N + col] = v;
      }
    }
  }
}

// ====== causal flash attention (R19-exact dataflow) + fused ffn weight cvts ======
// 1-D grid 9216: blocks [0,1024) = attn (bh = bid&31 -> XCD-local; g = 31-(bid>>5)
// -> LPT); [1024,5120) = ffn1_w cvt; [5120,9216) = ffn2_w cvt (backfill idle CUs
// under the latency-bound attn blocks; consumed >=2 kernels later in stream order).
__global__ __launch_bounds__(256) void attn_kernel(const u16* __restrict__ qkv,
                                                   u16* __restrict__ att,
                                                   const float* __restrict__ ffn1_w,
                                                   const float* __restrict__ ffn2_w,
                                                   u16* __restrict__ Wff1,
                                                   u16* __restrict__ Wff2){
  const int bid0 = blockIdx.x;
  const int tid = threadIdx.x;
  if (bid0 >= 1024){
    if (bid0 < 5120) cvt_body(ffn1_w, Wff1, (bid0 - 1024)*256 + tid);
    else             cvt_body(ffn2_w, Wff2, (bid0 - 5120)*256 + tid);
    return;
  }
  const int bh = bid0 & 31;           // XCD-local (id%8 == bh%8)
  const int g  = 31 - (bid0 >> 5);    // heavy blocks dispatch first
  const int bb = bh >> 4, hh = bh & 15;
  const int wid = tid >> 6, lane = tid & 63;
  const int half = wid >> 1;          // KV-range half
  const int p    = wid & 1;           // q-subtile
  const int l31 = lane & 31, h = lane >> 5;
  const u16* base = qkv + (size_t)bb * 2048 * 3072 + (size_t)hh * 192;

  __shared__ __align__(16) u16 Ks[2][64*72];   // 18432 B (combine O-buf reuses)
  __shared__ __align__(16) u16 Vt[2][64*80];   // 20480 B (combine ml-buf reuses)

  // staging mapping within each half's 128 threads
  const int th = tid & 127;
  const int sr = th >> 1, sh2 = (th & 1) * 32;
  const u16* kstage = base + (size_t)sr * 3072 + sh2;
  const int va = th >> 2, vd = (th & 3) * 16;
  const u16* vstage = base + (size_t)(2*va) * 3072 + 128 + vd;

  const int qrow0 = g*64 + p*32;
  const int q = qrow0 + l31;

  const float QSCALE = 0.125f * 1.44269504f;   // exp2 domain
  bf16x8 qb[4];
  {
    const u16* qp = base + (size_t)q * 3072 + 64 + 8*h;
    #pragma unroll
    for (int s = 0; s < 4; ++s)
      qb[s] = scale_bf16x8(*reinterpret_cast<const bf16x8*>(qp + 16*s), QSCALE);
  }

  f32x16 o0 = (f32x16)0.0f, o1 = (f32x16)0.0f;
  float m = -INFINITY, l = 0.0f;

  const int h0  = (g + 2) >> 1;            // ceil((g+1)/2) = half A length
  const int lo  = half ? h0 : 0;
  const int len = half ? (g + 1 - h0) : h0;

  uint4 ka0, ka1, ka2, ka3, v00, v01, v10, v11;
#define LOADREGS(t) do {                                               \
    const u16* kp = kstage + (size_t)(t) * 64 * 3072;                  \
    const u16* vp = vstage + (size_t)(t) * 64 * 3072;                  \
    ka0 = *reinterpret_cast<const uint4*>(kp);                         \
    ka1 = *reinterpret_cast<const uint4*>(kp + 8);                     \
    ka2 = *reinterpret_cast<const uint4*>(kp + 16);                    \
    ka3 = *reinterpret_cast<const uint4*>(kp + 24);                    \
    v00 = *reinterpret_cast<const uint4*>(vp);                         \
    v01 = *reinterpret_cast<const uint4*>(vp + 8);                     \
    v10 = *reinterpret_cast<const uint4*>(vp + 3072);                  \
    v11 = *reinterpret_cast<const uint4*>(vp + 3072 + 8);              \
  } while(0)

  if (len > 0) LOADREGS(lo);

  for (int it = 0; it < h0; ++it){
    const int kt = lo + it;
    const bool act = it < len;

    __syncthreads();               // previous tile's LDS reads complete (block-wide)
    if (act){
      *reinterpret_cast<uint4*>(&Ks[half][sr*72 + sh2])      = ka0;
      *reinterpret_cast<uint4*>(&Ks[half][sr*72 + sh2 + 8])  = ka1;
      *reinterpret_cast<uint4*>(&Ks[half][sr*72 + sh2 + 16]) = ka2;
      *reinterpret_cast<uint4*>(&Ks[half][sr*72 + sh2 + 24]) = ka3;
      u32 w00[4] = {v00.x, v00.y, v00.z, v00.w};
      u32 w01[4] = {v01.x, v01.y, v01.z, v01.w};
      u32 w10[4] = {v10.x, v10.y, v10.z, v10.w};
      u32 w11[4] = {v11.x, v11.y, v11.z, v11.w};
      // pack V[2va][d] | V[2va+1][d]<<16 with one v_perm_b32 per output word
      #pragma unroll
      for (int j = 0; j < 16; ++j){
        u32 a = (j < 8) ? w10[j>>1] : w11[(j-8)>>1];   // k row 2va+1 source
        u32 b = (j < 8) ? w00[j>>1] : w01[(j-8)>>1];   // k row 2va   source
        u32 packed = __builtin_amdgcn_perm(a, b, (j & 1) ? 0x07060302u : 0x05040100u);
        int d = vd + j;
        *reinterpret_cast<u32*>(&Vt[half][d*80 + (((va>>2) ^ (d>>3)) << 3) + 2*(va&3)]) =
            packed;
      }
    }
    __syncthreads();               // tile staged

    if (!act) continue;            // short half idles (after barriers)

    if (it + 1 < len) LOADREGS(kt + 1);   // prefetch next tile during compute

    const u16* KsC = &Ks[half][0];
    const u16* VtC = &Vt[half][0];

    // ---- S^T = K . Q'^T ----
    f32x16 s0 = (f32x16)0.0f, s1 = (f32x16)0.0f;
    __builtin_amdgcn_s_setprio(1);
    #pragma unroll
    for (int s = 0; s < 4; ++s){
      bf16x8 kf0 = *reinterpret_cast<const bf16x8*>(&KsC[l31*72      + 16*s + 8*h]);
      bf16x8 kf1 = *reinterpret_cast<const bf16x8*>(&KsC[(32+l31)*72 + 16*s + 8*h]);
      s0 = mfma32(kf0, qb[s], s0);
      s1 = mfma32(kf1, qb[s], s1);
    }
    __builtin_amdgcn_s_setprio(0);

    if (kt == g){                  // diagonal tile: causal mask
      #pragma unroll
      for (int r = 0; r < 16; ++r){
        int krow = kt*64 + (r&3) + 8*(r>>2) + 4*h;
        if (krow > q)      s0[r] = -INFINITY;
        if (krow + 32 > q) s1[r] = -INFINITY;
      }
    }

    // ---- per-lane softmax; max via max3-shaped tree (depth ~4) ----
    float t0_ = fmaxf(fmaxf(s0[0],  s0[1]),  s0[2]);
    float t1_ = fmaxf(fmaxf(s0[3],  s0[4]),  s0[5]);
    float t2_ = fmaxf(fmaxf(s0[6],  s0[7]),  s0[8]);
    float t3_ = fmaxf(fmaxf(s0[9],  s0[10]), s0[11]);
    float t4_ = fmaxf(fmaxf(s0[12], s0[13]), s0[14]);
    float t5_ = fmaxf(fmaxf(s0[15], s1[0]),  s1[1]);
    float t6_ = fmaxf(fmaxf(s1[2],  s1[3]),  s1[4]);
    float t7_ = fmaxf(fmaxf(s1[5],  s1[6]),  s1[7]);
    float t8_ = fmaxf(fmaxf(s1[8],  s1[9]),  s1[10]);
    float t9_ = fmaxf(fmaxf(s1[11], s1[12]), s1[13]);
    float ta_ = fmaxf(s1[14], s1[15]);
    float mxa = fmaxf(fmaxf(t0_, t1_), t2_);
    float mxb = fmaxf(fmaxf(t3_, t4_), t5_);
    float mxc = fmaxf(fmaxf(t6_, t7_), t8_);
    float mxd = fmaxf(t9_, ta_);
    float mx  = fmaxf(fmaxf(mxa, mxb), fmaxf(mxc, mxd));
    mx = fmaxf(mx, __shfl_xor(mx, 32, 64));
    if (__any(mx > m)){
      float mnew = fmaxf(m, mx);
      float al = exp2f(m - mnew);
      m = mnew;
      l *= al;
      o0 *= al;
      o1 *= al;
    }
    float p0[16], p1[16];
    float sa = 0.0f, sb = 0.0f, sc = 0.0f, sd = 0.0f;
    #pragma unroll
    for (int r = 0; r < 8; ++r){ p0[r] = exp2f(s0[r] - m); sa += p0[r]; }
    #pragma unroll
    for (int r = 8; r < 16; ++r){ p0[r] = exp2f(s0[r] - m); sb += p0[r]; }
    #pragma unroll
    for (int r = 0; r < 8; ++r){ p1[r] = exp2f(s1[r] - m); sc += p1[r]; }
    #pragma unroll
    for (int r = 8; r < 16; ++r){ p1[r] = exp2f(s1[r] - m); sd += p1[r]; }
    l += (sa + sb) + (sc + sd);

    u32 pk0[8], pk1[8];
    #pragma unroll
    for (int g4 = 0; g4 < 4; ++g4){
      pk0[2*g4]   = cvtpk(p0[4*g4],   p0[4*g4+1]);
      pk0[2*g4+1] = cvtpk(p0[4*g4+2], p0[4*g4+3]);
      pk1[2*g4]   = cvtpk(p1[4*g4],   p1[4*g4+1]);
      pk1[2*g4+1] = cvtpk(p1[4*g4+2], p1[4*g4+3]);
    }

    __builtin_amdgcn_s_setprio(1);
    #pragma unroll
    for (int s = 0; s < 4; ++s){
      const int gA = (s & 1) * 2;
      u32 oa0 = (s >> 1) ? pk1[2*gA]       : pk0[2*gA];
      u32 oa1 = (s >> 1) ? pk1[2*gA+1]     : pk0[2*gA+1];
      u32 ob0 = (s >> 1) ? pk1[2*(gA+1)]   : pk0[2*(gA+1)];
      u32 ob1 = (s >> 1) ? pk1[2*(gA+1)+1] : pk0[2*(gA+1)+1];
      u32 t0 = h ? oa0 : ob0;
      u32 t1 = h ? oa1 : ob1;
      u32 r0 = (u32)__shfl_xor((int)t0, 32, 64);
      u32 r1 = (u32)__shfl_xor((int)t1, 32, 64);
      u32 b0_ = h ? r0 : oa0;
      u32 b1_ = h ? r1 : oa1;
      u32 b2_ = h ? ob0 : r0;
      u32 b3_ = h ? ob1 : r1;
      bf16x8 pfrag = __builtin_bit_cast(bf16x8, make_uint4(b0_, b1_, b2_, b3_));
      bf16x8 vf0 = *reinterpret_cast<const bf16x8*>(
          &VtC[l31*80      + (((2*s + h) ^ (l31 >> 3)) << 3)]);
      bf16x8 vf1 = *reinterpret_cast<const bf16x8*>(
          &VtC[(32+l31)*80 + (((2*s + h) ^ ((32+l31) >> 3)) << 3)]);
      o0 = mfma32(vf0, pfrag, o0);
      o1 = mfma32(vf1, pfrag, o1);
    }
    __builtin_amdgcn_s_setprio(0);
  }

  // ---- in-block flash combine (A = half 0 waves, B = half 1 waves) ----
  __syncthreads();                       // all tile reads done; LDS reusable
  float* ob  = (float*)&Ks[0][0];        // [32 r][128 pl] = 16 KB, conflict-free
  float* mlb = (float*)&Vt[0][0];        // [128 pl][2]
  const int pl = p*64 + lane;

  l += __shfl_xor(l, 32, 64);            // full l per q for this half

  if (half == 1){
    #pragma unroll
    for (int r = 0; r < 16; ++r){
      ob[r*128 + pl]        = o0[r];
      ob[(16 + r)*128 + pl] = o1[r];
    }
    mlb[pl*2]     = m;
    mlb[pl*2 + 1] = l;
  }
  __syncthreads();
  if (half == 0){
    float mB = mlb[pl*2], lB = mlb[pl*2 + 1];
    float mS = fmaxf(m, mB);
    float sA = exp2f(m - mS), sB = exp2f(mB - mS);
    float inv = 1.0f / (l*sA + lB*sB);
    sA *= inv; sB *= inv;
    u16* orow = att + (size_t)(bb*2048 + q) * 1024 + hh*64;
    #pragma unroll
    for (int r = 0; r < 16; r += 2){
      int d0 = (r&3) + 8*(r>>2) + 4*h;
      float a0 = o0[r]*sA     + ob[r*128 + pl]*sB;
      float a1 = o0[r+1]*sA   + ob[(r+1)*128 + pl]*sB;
      float c0 = o1[r]*sA     + ob[(16+r)*128 + pl]*sB;
      float c1 = o1[r+1]*sA   + ob[(16+r+1)*128 + pl]*sB;
      *reinterpret_cast<u32*>(&orow[d0])      = cvtpk(a0, a1);
      *reinterpret_cast<u32*>(&orow[32 + d0]) = cvtpk(c0, c1);
    }
  }
#undef LOADREGS
}

extern "C" void kernel_launch(void* const* d_in, const int* in_sizes, int n_in,
                              void* d_out, int out_size, void* d_ws, size_t ws_size,
                              hipStream_t stream){
  const float* x        = (const float*)d_in[0];
  const float* ln1_w    = (const float*)d_in[1];
  const float* ln1_b    = (const float*)d_in[2];
  const float* c_proj_w = (const float*)d_in[3];
  const float* proj_w   = (const float*)d_in[4];
  const float* proj_b   = (const float*)d_in[5];
  const float* ln2_w    = (const float*)d_in[6];
  const float* ln2_b    = (const float*)d_in[7];
  const float* ffn1_w   = (const float*)d_in[8];
  const float* ffn1_b   = (const float*)d_in[9];
  const float* ffn2_w   = (const float*)d_in[10];
  const float* ffn2_b   = (const float*)d_in[11];

  // Workspace layout (80 MiB); tail region reused for ffn2 split-K partials.
  char* p = (char*)d_ws;
  u16* Wff1  = (u16*)p;  p += (size_t)4096*1024*2;   //  8 MiB
  u16* Wff2  = (u16*)p;  p += (size_t)1024*4096*2;   //  8 MiB
  u16* QKV   = (u16*)p;  p += (size_t)4096*3072*2;   // 24 MiB
  u16* ATT   = (u16*)p;  p += (size_t)4096*1024*2;   //  8 MiB
  u16* Wqkv  = (u16*)p;  p += (size_t)3072*1024*2;   //  6 MiB
  u16* Wproj = (u16*)p;  p += (size_t)1024*1024*2;   //  2 MiB
  u16* LNb   = (u16*)p;  p += (size_t)4096*1024*2;   //  8 MiB
  float* ACT2= (float*)p;                            // 16 MiB
  u16* FFN1  = QKV;
  u16* PART  = Wqkv;     // 32 MiB: Wqkv+Wproj+LNb+ACT2 all dead by ffn2 time

  // prep: c_proj/proj cvt + ln1 (ffn cvts ride along with attn)
  prep_kernel<<<8192, 256, 0, stream>>>(c_proj_w, proj_w, x, ln1_w, ln1_b,
                                        Wqkv, Wproj, LNb);
  gemm256<false,false,false><<<dim3(12,16,1), 512, 0, stream>>>(LNb, Wqkv, nullptr, QKV, 4096, 3072, 1024, 1024);
  attn_kernel<<<9216, 256, 0, stream>>>(QKV, ATT, ffn1_w, ffn2_w, Wff1, Wff2);
  gemm_bt<true ,true ,false,false><<<dim3(8,32), 256, 0, stream>>>(ATT, Wproj, proj_b, x, ACT2, 4096, 1024, 1024);
  ln_kernel<<<4096, 256, 0, stream>>>(ACT2, ln2_w, ln2_b, LNb);
  gemm256<true ,true ,false><<<dim3(16,16,1), 512, 0, stream>>>(LNb, Wff1, ffn1_b, FFN1, 4096, 4096, 1024, 1024);
  gemm256<false,false,true ><<<dim3(4,16,4), 512, 0, stream>>>(FFN1, Wff2, nullptr, PART, 4096, 1024, 4096, 1024);
  reduce4_kernel<<<2048, 256, 0, stream>>>(PART, x, ffn2_b, (float*)d_out);
}

// Round 22
// 221.285 us; speedup vs baseline: 1.0397x; 1.0117x over previous
//
#include <hip/hip_runtime.h>
#include <math.h>

typedef unsigned short u16;
typedef unsigned int u32;
typedef __attribute__((ext_vector_type(8))) __bf16 bf16x8;
typedef __attribute__((ext_vector_type(4))) float f32x4;
typedef __attribute__((ext_vector_type(16))) float f32x16;

#define DEVI __device__ __forceinline__

DEVI u16 f2bf(float f){
  u32 b = __builtin_bit_cast(u32, f);
  return (u16)((b + 0x7FFFu + ((b >> 16) & 1u)) >> 16);
}

// packed bf16 convert: lo = bf16(a), hi = bf16(b)
DEVI u32 cvtpk(float a, float b){
  u32 r;
  asm("v_cvt_pk_bf16_f32 %0, %1, %2" : "=v"(r) : "v"(a), "v"(b));
  return r;
}

DEVI f32x4 mfma16(bf16x8 a, bf16x8 b, f32x4 c){
  return __builtin_amdgcn_mfma_f32_16x16x32_bf16(a, b, c, 0, 0, 0);
}
DEVI f32x16 mfma32(bf16x8 a, bf16x8 b, f32x16 c){
  return __builtin_amdgcn_mfma_f32_32x32x16_bf16(a, b, c, 0, 0, 0);
}

// async global->LDS, 16B per lane; LDS dest = wave-uniform base + lane*16.
DEVI void gload16(const u16* g, u16* l){
  __builtin_amdgcn_global_load_lds(
      (const __attribute__((address_space(1))) u32*)g,
      (__attribute__((address_space(3))) u32*)l,
      16, 0, 0);
}

DEVI void phase_bar(){
  __builtin_amdgcn_sched_barrier(0);
  __builtin_amdgcn_s_barrier();
  __builtin_amdgcn_sched_barrier(0);
}

DEVI bf16x8 scale_bf16x8(bf16x8 v, float s){
  u32 w[4]; __builtin_memcpy(w, &v, 16);
  u32 o[4];
  #pragma unroll
  for (int i = 0; i < 4; ++i){
    float f0 = __builtin_bit_cast(float, (w[i] & 0xFFFFu) << 16) * s;
    float f1 = __builtin_bit_cast(float, w[i] & 0xFFFF0000u) * s;
    o[i] = (u32)f2bf(f0) | ((u32)f2bf(f1) << 16);
  }
  bf16x8 r; __builtin_memcpy(&r, o, 16);
  return r;
}

// ---------------- cvt body: 4 f32 -> 4 bf16 per thread ----------------
DEVI void cvt_body(const float* __restrict__ in, u16* __restrict__ out, int i){
  float4 v = reinterpret_cast<const float4*>(in)[i];
  u32 lo = (u32)f2bf(v.x) | ((u32)f2bf(v.y) << 16);
  u32 hi = (u32)f2bf(v.z) | ((u32)f2bf(v.w) << 16);
  reinterpret_cast<uint2*>(out)[i] = make_uint2(lo, hi);
}

// ---------------- LN body: f32 in, bf16 out, row length 1024 ----------------
DEVI void ln_body(const float* __restrict__ x, const float* __restrict__ w,
                  const float* __restrict__ b, u16* __restrict__ out,
                  int row, int tid, float* red){
  const float4 v = reinterpret_cast<const float4*>(x + (size_t)row * 1024)[tid];
  float s  = v.x + v.y + v.z + v.w;
  float ss = v.x*v.x + v.y*v.y + v.z*v.z + v.w*v.w;
  #pragma unroll
  for (int m = 1; m < 64; m <<= 1){
    s  += __shfl_xor(s,  m, 64);
    ss += __shfl_xor(ss, m, 64);
  }
  int wid = tid >> 6, lane = tid & 63;
  if (lane == 0){ red[wid] = s; red[4 + wid] = ss; }
  __syncthreads();
  s  = red[0] + red[1] + red[2] + red[3];
  ss = red[4] + red[5] + red[6] + red[7];
  float mu   = s * (1.0f/1024.0f);
  float var  = ss * (1.0f/1024.0f) - mu*mu;
  float rstd = rsqrtf(var + 1e-5f);
  const float4 wv = reinterpret_cast<const float4*>(w)[tid];
  const float4 bv = reinterpret_cast<const float4*>(b)[tid];
  u32 lo = (u32)f2bf((v.x-mu)*rstd*wv.x + bv.x) | ((u32)f2bf((v.y-mu)*rstd*wv.y + bv.y) << 16);
  u32 hi = (u32)f2bf((v.z-mu)*rstd*wv.z + bv.z) | ((u32)f2bf((v.w-mu)*rstd*wv.w + bv.w) << 16);
  reinterpret_cast<uint2*>(out + (size_t)row*1024)[tid] = make_uint2(lo, hi);
}

// ------- prep: c_proj & proj weight cvts + ln1 (ffn cvts ride inside attn blocks) ---
// blocks [0,3072): c_proj_w->Wqkv | [3072,4096): proj_w->Wproj | [4096,8192): ln1
__global__ __launch_bounds__(256) void prep_kernel(const float* __restrict__ c_proj_w,
                                                   const float* __restrict__ proj_w,
                                                   const float* __restrict__ x,
                                                   const float* __restrict__ ln1_w,
                                                   const float* __restrict__ ln1_b,
                                                   u16* __restrict__ Wqkv,
                                                   u16* __restrict__ Wproj,
                                                   u16* __restrict__ LNb){
  __shared__ float red[8];
  const int bid = blockIdx.x;
  const int tid = threadIdx.x;
  if (bid < 3072){
    cvt_body(c_proj_w, Wqkv, bid*256 + tid);
  } else if (bid < 4096){
    cvt_body(proj_w, Wproj, (bid - 3072)*256 + tid);
  } else {
    ln_body(x, ln1_w, ln1_b, LNb, bid - 4096, tid, red);
  }
}

// ---------------- standalone LN (for ln2) ----------------
__global__ __launch_bounds__(256) void ln_kernel(const float* __restrict__ x,
                                                 const float* __restrict__ w,
                                                 const float* __restrict__ b,
                                                 u16* __restrict__ out){
  __shared__ float red[8];
  ln_body(x, w, b, out, blockIdx.x, threadIdx.x, red);
}

// ---------------- reduce: out = x + bias + sum of 4 bf16 partials (f32 out) --------
__global__ __launch_bounds__(256) void reduce4_kernel(const u16* __restrict__ P,
                                                      const float* __restrict__ x,
                                                      const float* __restrict__ bias,
                                                      float* __restrict__ out){
  const size_t i8 = ((size_t)blockIdx.x * 256 + threadIdx.x) * 8;
  const size_t PS = (size_t)4096 * 1024;
  const int col0 = (int)(i8 & 1023);
  float acc[8];
  #pragma unroll
  for (int j = 0; j < 8; ++j) acc[j] = bias[col0 + j];
  #pragma unroll
  for (int s = 0; s < 4; ++s){
    uint4 d = *reinterpret_cast<const uint4*>(P + s*PS + i8);
    u32 w[4] = {d.x, d.y, d.z, d.w};
    #pragma unroll
    for (int j = 0; j < 8; ++j){
      u32 bits = ((w[j>>1] >> (16*(j&1))) & 0xFFFFu) << 16;
      acc[j] += __builtin_bit_cast(float, bits);
    }
  }
  float4 xv0 = reinterpret_cast<const float4*>(x + i8)[0];
  float4 xv1 = reinterpret_cast<const float4*>(x + i8)[1];
  acc[0]+=xv0.x; acc[1]+=xv0.y; acc[2]+=xv0.z; acc[3]+=xv0.w;
  acc[4]+=xv1.x; acc[5]+=xv1.y; acc[6]+=xv1.z; acc[7]+=xv1.w;
  reinterpret_cast<float4*>(out + i8)[0] = make_float4(acc[0],acc[1],acc[2],acc[3]);
  reinterpret_cast<float4*>(out + i8)[1] = make_float4(acc[4],acc[5],acc[6],acc[7]);
}

// ============ 256x256 8-phase GEMM: C = A(M x lda) * W(N x lda)^T, bf16 out ========
template<bool HAS_BIAS, bool RELU, bool SPLIT>
__global__ __launch_bounds__(512, 2) void gemm256(const u16* __restrict__ A,
                                                  const u16* __restrict__ W,
                                                  const float* __restrict__ bias,
                                                  u16* __restrict__ outp,
                                                  int M, int N, int lda, int kLen){
  const int tid = threadIdx.x;
  const int wid = tid >> 6, lane = tid & 63;
  const int l16 = lane & 15, lhi = lane >> 4;
  const int wr = wid >> 2, wc = wid & 3;

  const int gx = gridDim.x, gy = gridDim.y;
  const int nwg = gx * gy * gridDim.z;
  const int bid = (blockIdx.z * gy + blockIdx.y) * gx + blockIdx.x;
  const int swz = (bid & 7) * (nwg >> 3) + (bid >> 3);
  const int col = swz % gx;
  const int rs  = swz / gx;
  const int row = rs % gy;
  const int ksp = rs / gy;
  const int brow = row * 256;
  const int bcol = col * 256;
  const size_t koff = (size_t)ksp * kLen;
  if (SPLIT) outp += (size_t)ksp * M * N;

  __shared__ u16 LDS[2][2][2][256*32];   // 128 KiB

  const int srow = tid >> 2;
  const int cg   = (tid & 3) ^ ((tid >> 3) & 3);
  const u16* gA = A + (size_t)(brow + srow) * lda + koff + cg*8;
  const u16* gW = W + (size_t)(bcol + srow) * lda + koff + cg*8;
  const size_t rK = (size_t)128 * lda;

#define STAGE(buf, mat, ks, t) do {                                   \
    const u16* _s = ((mat) ? gW : gA) + (t)*64 + (ks)*32;             \
    u16* _d = &LDS[buf][mat][ks][(wid*16)*32];                        \
    gload16(_s,      _d);                                             \
    gload16(_s + rK, _d + 128*32);                                    \
  } while(0)

  const int cswz = (lhi ^ ((l16 >> 1) & 3)) * 8;
  const int aoff = (wr*128 + l16)*32 + cswz;
  const int boff = (wc*64  + l16)*32 + cswz;
#define RDA(buf, ks, m) (*reinterpret_cast<const bf16x8*>(&LDS[buf][0][ks][aoff + (m)*512]))
#define RDB(buf, ks, n) (*reinterpret_cast<const bf16x8*>(&LDS[buf][1][ks][boff + (n)*512]))

  f32x4 acc[8][4] = {};
  bf16x8 a[8], b0, b1;

#define MFMA_PH(n0, n1) do {                                          \
    __builtin_amdgcn_s_setprio(1);                                    \
    _Pragma("unroll")                                                 \
    for (int m = 0; m < 8; ++m){                                      \
      acc[m][n0] = mfma16(a[m], b0, acc[m][n0]);                      \
      acc[m][n1] = mfma16(a[m], b1, acc[m][n1]);                      \
    }                                                                 \
    __builtin_amdgcn_s_setprio(0);                                    \
  } while(0)

  const int NITER = kLen >> 7;

  STAGE(0,0,0,0); STAGE(0,1,0,0); STAGE(0,0,1,0); STAGE(0,1,1,0);
  STAGE(1,0,0,1); STAGE(1,1,0,1);
  asm volatile("s_waitcnt vmcnt(4)" ::: "memory");
  phase_bar();

  for (int j = 0; j < NITER; ++j){
    const int t0 = 2*j, t1 = 2*j + 1;
    const bool more = (j + 1 < NITER);

    #pragma unroll
    for (int m = 0; m < 8; ++m) a[m] = RDA(0,0,m);
    b0 = RDB(0,0,0); b1 = RDB(0,0,1);
    STAGE(1,0,1,t1);
    phase_bar();
    MFMA_PH(0,1);
    phase_bar();
    b0 = RDB(0,0,2); b1 = RDB(0,0,3);
    STAGE(1,1,1,t1);
    phase_bar();
    MFMA_PH(2,3);
    phase_bar();
    #pragma unroll
    for (int m = 0; m < 8; ++m) a[m] = RDA(0,1,m);
    b0 = RDB(0,1,0); b1 = RDB(0,1,1);
    if (more) STAGE(0,0,0,t0+2);
    phase_bar();
    MFMA_PH(0,1);
    phase_bar();
    b0 = RDB(0,1,2); b1 = RDB(0,1,3);
    if (more){ STAGE(0,1,0,t0+2); asm volatile("s_waitcnt vmcnt(4)" ::: "memory"); }
    else     {                    asm volatile("s_waitcnt vmcnt(0)" ::: "memory"); }
    phase_bar();
    MFMA_PH(2,3);
    phase_bar();
    #pragma unroll
    for (int m = 0; m < 8; ++m) a[m] = RDA(1,0,m);
    b0 = RDB(1,0,0); b1 = RDB(1,0,1);
    if (more) STAGE(0,0,1,t0+2);
    phase_bar();
    MFMA_PH(0,1);
    phase_bar();
    b0 = RDB(1,0,2); b1 = RDB(1,0,3);
    if (more) STAGE(0,1,1,t0+2);
    phase_bar();
    MFMA_PH(2,3);
    phase_bar();
    #pragma unroll
    for (int m = 0; m < 8; ++m) a[m] = RDA(1,1,m);
    b0 = RDB(1,1,0); b1 = RDB(1,1,1);
    if (more) STAGE(1,0,0,t1+2);
    phase_bar();
    MFMA_PH(0,1);
    phase_bar();
    b0 = RDB(1,1,2); b1 = RDB(1,1,3);
    if (more){ STAGE(1,1,0,t1+2); asm volatile("s_waitcnt vmcnt(4)" ::: "memory"); }
    phase_bar();
    MFMA_PH(2,3);
    phase_bar();
  }
  __builtin_amdgcn_sched_barrier(0);

  const int row0 = brow + wr*128;
  const int col0 = bcol + wc*64;
  #pragma unroll
  for (int m = 0; m < 8; ++m){
    #pragma unroll
    for (int n = 0; n < 4; ++n){
      #pragma unroll
      for (int r = 0; r < 4; ++r){
        int row_ = row0 + m*16 + 4*lhi + r;
        int col_ = col0 + n*16 + l16;
        float v = acc[m][n][r];
        if constexpr (HAS_BIAS) v += bias[col_];
        if constexpr (RELU)     v = fmaxf(v, 0.0f);
        outp[(size_t)row_ * N + col_] = f2bf(v);
      }
    }
  }
#undef STAGE
#undef RDA
#undef RDB
#undef MFMA_PH
}

// ---------------- GEMM 128x128 (R7 structure) for proj ----------------
template<bool HAS_BIAS, bool HAS_RES, bool RELU, bool OUT_BF16>
__global__ __launch_bounds__(256) void gemm_bt(const u16* __restrict__ A,
                                               const u16* __restrict__ W,
                                               const float* __restrict__ bias,
                                               const float* __restrict__ res,
                                               void* __restrict__ outp,
                                               int M, int N, int K){
  const int tid = threadIdx.x;
  const int wid = tid >> 6, lane = tid & 63;
  const int l16 = lane & 15, lhi = lane >> 4;
  const int wr = wid >> 1, wc = wid & 1;

  const int gx = gridDim.x;
  const int nwg = gx * gridDim.y;
  const int bid = blockIdx.y * gx + blockIdx.x;
  const int swz = (bid & 7) * (nwg >> 3) + (bid >> 3);
  const int brow = (swz / gx) * 128;
  const int bcol = (swz % gx) * 128;

  __shared__ u16 As[2][128*32];
  __shared__ u16 Bs[2][128*32];

  const int srow = wid*32 + (lane >> 2);
  const int schk = lane & 3;
  const u16* gA0 = A + (size_t)(brow + srow)      * K + schk*8;
  const u16* gA1 = A + (size_t)(brow + srow + 16) * K + schk*8;
  const u16* gW0 = W + (size_t)(bcol + srow)      * K + schk*8;
  const u16* gW1 = W + (size_t)(bcol + srow + 16) * K + schk*8;
  const int ldsA0 = (wid*32)*32, ldsA1 = (wid*32 + 16)*32;

  f32x4 acc[4][4] = {};

  gload16(gA0, &As[0][ldsA0]);
  gload16(gA1, &As[0][ldsA1]);
  gload16(gW0, &Bs[0][ldsA0]);
  gload16(gW1, &Bs[0][ldsA1]);

  int cur = 0;
  for (int k0 = 0; k0 < K; k0 += 32){
    __syncthreads();
    if (k0 + 32 < K){
      gload16(gA0 + k0 + 32, &As[cur^1][ldsA0]);
      gload16(gA1 + k0 + 32, &As[cur^1][ldsA1]);
      gload16(gW0 + k0 + 32, &Bs[cur^1][ldsA0]);
      gload16(gW1 + k0 + 32, &Bs[cur^1][ldsA1]);
    }
    bf16x8 af[4], bfr[4];
    #pragma unroll
    for (int m = 0; m < 4; ++m)
      af[m]  = *reinterpret_cast<const bf16x8*>(&As[cur][(wr*64 + m*16 + l16)*32 + 8*lhi]);
    #pragma unroll
    for (int n = 0; n < 4; ++n)
      bfr[n] = *reinterpret_cast<const bf16x8*>(&Bs[cur][(wc*64 + n*16 + l16)*32 + 8*lhi]);
    #pragma unroll
    for (int m = 0; m < 4; ++m){
      #pragma unroll
      for (int n = 0; n < 4; ++n){
        acc[m][n] = mfma16(af[m], bfr[n], acc[m][n]);
      }
    }
    cur ^= 1;
  }

  const int row0 = brow + wr*64;
  const int col0 = bcol + wc*64;
  #pragma unroll
  for (int m = 0; m < 4; ++m){
    #pragma unroll
    for (int n = 0; n < 4; ++n){
      #pragma unroll
      for (int r = 0; r < 4; ++r){
        int row = row0 + m*16 + 4*lhi + r;
        int col = col0 + n*16 + l16;
        float v = acc[m][n][r];
        if constexpr (HAS_BIAS) v += bias[col];
        if constexpr (RELU)     v = fmaxf(v, 0.0f);
        if constexpr (HAS_RES)  v += res[(size_t)row * N + col];
        if constexpr (OUT_BF16) ((u16*)outp)[(size_t)row * N + col] = f2bf(v);
        else                    ((float*)outp)[(size_t)row * N + col] = v;
      }
    }
  }
}

// ====== causal flash attention (R19-exact dataflow) + in-block ffn cvt TAIL ======
// grid 1024; bh = bid&31 (XCD-local), g = 31-(bid>>5) (LPT). After the combine,
// each block grid-strides over 8 of 8192 cvt chunks (Wff1/Wff2): light attn blocks
// finish early and convert weights while heavy blocks still compute — overlap
// within the same 4-block/CU residency footprint (no cvt-only block slots).
__global__ __launch_bounds__(256) void attn_kernel(const u16* __restrict__ qkv,
                                                   u16* __restrict__ att,
                                                   const float* __restrict__ ffn1_w,
                                                   const float* __restrict__ ffn2_w,
                                                   u16* __restrict__ Wff1,
                                                   u16* __restrict__ Wff2){
  const int bid0 = blockIdx.x;
  const int tid = threadIdx.x;
  const int bh = bid0 & 31;           // XCD-local (id%8 == bh%8)
  const int g  = 31 - (bid0 >> 5);    // heavy blocks dispatch first
  const int bb = bh >> 4, hh = bh & 15;
  const int wid = tid >> 6, lane = tid & 63;
  const int half = wid >> 1;          // KV-range half
  const int p    = wid & 1;           // q-subtile
  const int l31 = lane & 31, h = lane >> 5;
  const u16* base = qkv + (size_t)bb * 2048 * 3072 + (size_t)hh * 192;

  __shared__ __align__(16) u16 Ks[2][64*72];   // 18432 B (combine O-buf reuses)
  __shared__ __align__(16) u16 Vt[2][64*80];   // 20480 B (combine ml-buf reuses)

  // staging mapping within each half's 128 threads
  const int th = tid & 127;
  const int sr = th >> 1, sh2 = (th & 1) * 32;
  const u16* kstage = base + (size_t)sr * 3072 + sh2;
  const int va = th >> 2, vd = (th & 3) * 16;
  const u16* vstage = base + (size_t)(2*va) * 3072 + 128 + vd;

  const int qrow0 = g*64 + p*32;
  const int q = qrow0 + l31;

  const float QSCALE = 0.125f * 1.44269504f;   // exp2 domain
  bf16x8 qb[4];
  {
    const u16* qp = base + (size_t)q * 3072 + 64 + 8*h;
    #pragma unroll
    for (int s = 0; s < 4; ++s)
      qb[s] = scale_bf16x8(*reinterpret_cast<const bf16x8*>(qp + 16*s), QSCALE);
  }

  f32x16 o0 = (f32x16)0.0f, o1 = (f32x16)0.0f;
  float m = -INFINITY, l = 0.0f;

  const int h0  = (g + 2) >> 1;            // ceil((g+1)/2) = half A length
  const int lo  = half ? h0 : 0;
  const int len = half ? (g + 1 - h0) : h0;

  uint4 ka0, ka1, ka2, ka3, v00, v01, v10, v11;
#define LOADREGS(t) do {                                               \
    const u16* kp = kstage + (size_t)(t) * 64 * 3072;                  \
    const u16* vp = vstage + (size_t)(t) * 64 * 3072;                  \
    ka0 = *reinterpret_cast<const uint4*>(kp);                         \
    ka1 = *reinterpret_cast<const uint4*>(kp + 8);                     \
    ka2 = *reinterpret_cast<const uint4*>(kp + 16);                    \
    ka3 = *reinterpret_cast<const uint4*>(kp + 24);                    \
    v00 = *reinterpret_cast<const uint4*>(vp);                         \
    v01 = *reinterpret_cast<const uint4*>(vp + 8);                     \
    v10 = *reinterpret_cast<const uint4*>(vp + 3072);                  \
    v11 = *reinterpret_cast<const uint4*>(vp + 3072 + 8);              \
  } while(0)

  if (len > 0) LOADREGS(lo);

  for (int it = 0; it < h0; ++it){
    const int kt = lo + it;
    const bool act = it < len;

    __syncthreads();               // previous tile's LDS reads complete (block-wide)
    if (act){
      *reinterpret_cast<uint4*>(&Ks[half][sr*72 + sh2])      = ka0;
      *reinterpret_cast<uint4*>(&Ks[half][sr*72 + sh2 + 8])  = ka1;
      *reinterpret_cast<uint4*>(&Ks[half][sr*72 + sh2 + 16]) = ka2;
      *reinterpret_cast<uint4*>(&Ks[half][sr*72 + sh2 + 24]) = ka3;
      u32 w00[4] = {v00.x, v00.y, v00.z, v00.w};
      u32 w01[4] = {v01.x, v01.y, v01.z, v01.w};
      u32 w10[4] = {v10.x, v10.y, v10.z, v10.w};
      u32 w11[4] = {v11.x, v11.y, v11.z, v11.w};
      // pack V[2va][d] | V[2va+1][d]<<16 with one v_perm_b32 per output word
      #pragma unroll
      for (int j = 0; j < 16; ++j){
        u32 a = (j < 8) ? w10[j>>1] : w11[(j-8)>>1];   // k row 2va+1 source
        u32 b = (j < 8) ? w00[j>>1] : w01[(j-8)>>1];   // k row 2va   source
        u32 packed = __builtin_amdgcn_perm(a, b, (j & 1) ? 0x07060302u : 0x05040100u);
        int d = vd + j;
        *reinterpret_cast<u32*>(&Vt[half][d*80 + (((va>>2) ^ (d>>3)) << 3) + 2*(va&3)]) =
            packed;
      }
    }
    __syncthreads();               // tile staged

    if (!act) continue;            // short half idles (after barriers)

    if (it + 1 < len) LOADREGS(kt + 1);   // prefetch next tile during compute

    const u16* KsC = &Ks[half][0];
    const u16* VtC = &Vt[half][0];

    // ---- S^T = K . Q'^T ----
    f32x16 s0 = (f32x16)0.0f, s1 = (f32x16)0.0f;
    __builtin_amdgcn_s_setprio(1);
    #pragma unroll
    for (int s = 0; s < 4; ++s){
      bf16x8 kf0 = *reinterpret_cast<const bf16x8*>(&KsC[l31*72      + 16*s + 8*h]);
      bf16x8 kf1 = *reinterpret_cast<const bf16x8*>(&KsC[(32+l31)*72 + 16*s + 8*h]);
      s0 = mfma32(kf0, qb[s], s0);
      s1 = mfma32(kf1, qb[s], s1);
    }
    __builtin_amdgcn_s_setprio(0);

    if (kt == g){                  // diagonal tile: causal mask
      #pragma unroll
      for (int r = 0; r < 16; ++r){
        int krow = kt*64 + (r&3) + 8*(r>>2) + 4*h;
        if (krow > q)      s0[r] = -INFINITY;
        if (krow + 32 > q) s1[r] = -INFINITY;
      }
    }

    // ---- per-lane softmax; max via max3-shaped tree (depth ~4) ----
    float t0_ = fmaxf(fmaxf(s0[0],  s0[1]),  s0[2]);
    float t1_ = fmaxf(fmaxf(s0[3],  s0[4]),  s0[5]);
    float t2_ = fmaxf(fmaxf(s0[6],  s0[7]),  s0[8]);
    float t3_ = fmaxf(fmaxf(s0[9],  s0[10]), s0[11]);
    float t4_ = fmaxf(fmaxf(s0[12], s0[13]), s0[14]);
    float t5_ = fmaxf(fmaxf(s0[15], s1[0]),  s1[1]);
    float t6_ = fmaxf(fmaxf(s1[2],  s1[3]),  s1[4]);
    float t7_ = fmaxf(fmaxf(s1[5],  s1[6]),  s1[7]);
    float t8_ = fmaxf(fmaxf(s1[8],  s1[9]),  s1[10]);
    float t9_ = fmaxf(fmaxf(s1[11], s1[12]), s1[13]);
    float ta_ = fmaxf(s1[14], s1[15]);
    float mxa = fmaxf(fmaxf(t0_, t1_), t2_);
    float mxb = fmaxf(fmaxf(t3_, t4_), t5_);
    float mxc = fmaxf(fmaxf(t6_, t7_), t8_);
    float mxd = fmaxf(t9_, ta_);
    float mx  = fmaxf(fmaxf(mxa, mxb), fmaxf(mxc, mxd));
    mx = fmaxf(mx, __shfl_xor(mx, 32, 64));
    if (__any(mx > m)){
      float mnew = fmaxf(m, mx);
      float al = exp2f(m - mnew);
      m = mnew;
      l *= al;
      o0 *= al;
      o1 *= al;
    }
    float p0[16], p1[16];
    float sa = 0.0f, sb = 0.0f, sc = 0.0f, sd = 0.0f;
    #pragma unroll
    for (int r = 0; r < 8; ++r){ p0[r] = exp2f(s0[r] - m); sa += p0[r]; }
    #pragma unroll
    for (int r = 8; r < 16; ++r){ p0[r] = exp2f(s0[r] - m); sb += p0[r]; }
    #pragma unroll
    for (int r = 0; r < 8; ++r){ p1[r] = exp2f(s1[r] - m); sc += p1[r]; }
    #pragma unroll
    for (int r = 8; r < 16; ++r){ p1[r] = exp2f(s1[r] - m); sd += p1[r]; }
    l += (sa + sb) + (sc + sd);

    u32 pk0[8], pk1[8];
    #pragma unroll
    for (int g4 = 0; g4 < 4; ++g4){
      pk0[2*g4]   = cvtpk(p0[4*g4],   p0[4*g4+1]);
      pk0[2*g4+1] = cvtpk(p0[4*g4+2], p0[4*g4+3]);
      pk1[2*g4]   = cvtpk(p1[4*g4],   p1[4*g4+1]);
      pk1[2*g4+1] = cvtpk(p1[4*g4+2], p1[4*g4+3]);
    }

    __builtin_amdgcn_s_setprio(1);
    #pragma unroll
    for (int s = 0; s < 4; ++s){
      const int gA = (s & 1) * 2;
      u32 oa0 = (s >> 1) ? pk1[2*gA]       : pk0[2*gA];
      u32 oa1 = (s >> 1) ? pk1[2*gA+1]     : pk0[2*gA+1];
      u32 ob0 = (s >> 1) ? pk1[2*(gA+1)]   : pk0[2*(gA+1)];
      u32 ob1 = (s >> 1) ? pk1[2*(gA+1)+1] : pk0[2*(gA+1)+1];
      u32 t0 = h ? oa0 : ob0;
      u32 t1 = h ? oa1 : ob1;
      u32 r0 = (u32)__shfl_xor((int)t0, 32, 64);
      u32 r1 = (u32)__shfl_xor((int)t1, 32, 64);
      u32 b0_ = h ? r0 : oa0;
      u32 b1_ = h ? r1 : oa1;
      u32 b2_ = h ? ob0 : r0;
      u32 b3_ = h ? ob1 : r1;
      bf16x8 pfrag = __builtin_bit_cast(bf16x8, make_uint4(b0_, b1_, b2_, b3_));
      bf16x8 vf0 = *reinterpret_cast<const bf16x8*>(
          &VtC[l31*80      + (((2*s + h) ^ (l31 >> 3)) << 3)]);
      bf16x8 vf1 = *reinterpret_cast<const bf16x8*>(
          &VtC[(32+l31)*80 + (((2*s + h) ^ ((32+l31) >> 3)) << 3)]);
      o0 = mfma32(vf0, pfrag, o0);
      o1 = mfma32(vf1, pfrag, o1);
    }
    __builtin_amdgcn_s_setprio(0);
  }

  // ---- in-block flash combine (A = half 0 waves, B = half 1 waves) ----
  __syncthreads();                       // all tile reads done; LDS reusable
  float* ob  = (float*)&Ks[0][0];        // [32 r][128 pl] = 16 KB, conflict-free
  float* mlb = (float*)&Vt[0][0];        // [128 pl][2]
  const int pl = p*64 + lane;

  l += __shfl_xor(l, 32, 64);            // full l per q for this half

  if (half == 1){
    #pragma unroll
    for (int r = 0; r < 16; ++r){
      ob[r*128 + pl]        = o0[r];
      ob[(16 + r)*128 + pl] = o1[r];
    }
    mlb[pl*2]     = m;
    mlb[pl*2 + 1] = l;
  }
  __syncthreads();
  if (half == 0){
    float mB = mlb[pl*2], lB = mlb[pl*2 + 1];
    float mS = fmaxf(m, mB);
    float sA = exp2f(m - mS), sB = exp2f(mB - mS);
    float inv = 1.0f / (l*sA + lB*sB);
    sA *= inv; sB *= inv;
    u16* orow = att + (size_t)(bb*2048 + q) * 1024 + hh*64;
    #pragma unroll
    for (int r = 0; r < 16; r += 2){
      int d0 = (r&3) + 8*(r>>2) + 4*h;
      float a0 = o0[r]*sA     + ob[r*128 + pl]*sB;
      float a1 = o0[r+1]*sA   + ob[(r+1)*128 + pl]*sB;
      float c0 = o1[r]*sA     + ob[(16+r)*128 + pl]*sB;
      float c1 = o1[r+1]*sA   + ob[(16+r+1)*128 + pl]*sB;
      *reinterpret_cast<u32*>(&orow[d0])      = cvtpk(a0, a1);
      *reinterpret_cast<u32*>(&orow[32 + d0]) = cvtpk(c0, c1);
    }
  }

  // ---- tail: ffn weight cvts, grid-strided over attn blocks (8 chunks each) ----
  #pragma unroll
  for (int c = 0; c < 8; ++c){
    int chunk = bid0 + c * 1024;        // 0..8191
    if (chunk < 4096) cvt_body(ffn1_w, Wff1, chunk*256 + tid);
    else              cvt_body(ffn2_w, Wff2, (chunk - 4096)*256 + tid);
  }
#undef LOADREGS
}

extern "C" void kernel_launch(void* const* d_in, const int* in_sizes, int n_in,
                              void* d_out, int out_size, void* d_ws, size_t ws_size,
                              hipStream_t stream){
  const float* x        = (const float*)d_in[0];
  const float* ln1_w    = (const float*)d_in[1];
  const float* ln1_b    = (const float*)d_in[2];
  const float* c_proj_w = (const float*)d_in[3];
  const float* proj_w   = (const float*)d_in[4];
  const float* proj_b   = (const float*)d_in[5];
  const float* ln2_w    = (const float*)d_in[6];
  const float* ln2_b    = (const float*)d_in[7];
  const float* ffn1_w   = (const float*)d_in[8];
  const float* ffn1_b   = (const float*)d_in[9];
  const float* ffn2_w   = (const float*)d_in[10];
  const float* ffn2_b   = (const float*)d_in[11];

  // Workspace layout (80 MiB); tail region reused for ffn2 split-K partials.
  char* p = (char*)d_ws;
  u16* Wff1  = (u16*)p;  p += (size_t)4096*1024*2;   //  8 MiB
  u16* Wff2  = (u16*)p;  p += (size_t)1024*4096*2;   //  8 MiB
  u16* QKV   = (u16*)p;  p += (size_t)4096*3072*2;   // 24 MiB
  u16* ATT   = (u16*)p;  p += (size_t)4096*1024*2;   //  8 MiB
  u16* Wqkv  = (u16*)p;  p += (size_t)3072*1024*2;   //  6 MiB
  u16* Wproj = (u16*)p;  p += (size_t)1024*1024*2;   //  2 MiB
  u16* LNb   = (u16*)p;  p += (size_t)4096*1024*2;   //  8 MiB
  float* ACT2= (float*)p;                            // 16 MiB
  u16* FFN1  = QKV;
  u16* PART  = Wqkv;     // 32 MiB: Wqkv+Wproj+LNb+ACT2 all dead by ffn2 time

  // prep: c_proj/proj cvt + ln1 (ffn cvts ride inside attn blocks)
  prep_kernel<<<8192, 256, 0, stream>>>(c_proj_w, proj_w, x, ln1_w, ln1_b,
                                        Wqkv, Wproj, LNb);
  gemm256<false,false,false><<<dim3(12,16,1), 512, 0, stream>>>(LNb, Wqkv, nullptr, QKV, 4096, 3072, 1024, 1024);
  attn_kernel<<<1024, 256, 0, stream>>>(QKV, ATT, ffn1_w, ffn2_w, Wff1, Wff2);
  gemm_bt<true ,true ,false,false><<<dim3(8,32), 256, 0, stream>>>(ATT, Wproj, proj_b, x, ACT2, 4096, 1024, 1024);
  ln_kernel<<<4096, 256, 0, stream>>>(ACT2, ln2_w, ln2_b, LNb);
  gemm256<true ,true ,false><<<dim3(16,16,1), 512, 0, stream>>>(LNb, Wff1, ffn1_b, FFN1, 4096, 4096, 1024, 1024);
  gemm256<false,false,true ><<<dim3(4,16,4), 512, 0, stream>>>(FFN1, Wff2, nullptr, PART, 4096, 1024, 4096, 1024);
  reduce4_kernel<<<2048, 256, 0, stream>>>(PART, x, ffn2_b, (float*)d_out);
}